// Round 1
// baseline (202.578 us; speedup 1.0000x reference)
//
#include <hip/hip_runtime.h>

#define NB 16
#define NM 32
#define NA 8400
#define NCC 80
#define NREG 64
#define A0 6400
#define A1 1600
#define A2 400

// ---------- device helpers ----------

__device__ __forceinline__ void anch(int a, float& ax, float& ay, float& s, int& lvl, int& p) {
  if (a < A0)            { lvl = 0; p = a;          s = 8.f;  ax = (float)(p % 80); ay = (float)(p / 80); }
  else if (a < A0 + A1)  { lvl = 1; p = a - A0;     s = 16.f; ax = (float)(p % 40); ay = (float)(p / 40); }
  else                   { lvl = 2; p = a - A0 - A1; s = 32.f; ax = (float)(p % 20); ay = (float)(p / 20); }
}

__device__ __forceinline__ float cls_at(const float* c0, const float* c1, const float* c2,
                                        int b, int ch, int a) {
  if (a < A0)           return c0[((size_t)(b * NCC + ch)) * A0 + a];
  if (a < A0 + A1)      return c1[((size_t)(b * NCC + ch)) * A1 + (a - A0)];
  return c2[((size_t)(b * NCC + ch)) * A2 + (a - A0 - A1)];
}

__device__ __forceinline__ float reg_at(const float* r0, const float* r1, const float* r2,
                                        int b, int ch, int lvl, int p) {
  if (lvl == 0) return r0[((size_t)(b * NREG + ch)) * A0 + p];
  if (lvl == 1) return r1[((size_t)(b * NREG + ch)) * A1 + p];
  return r2[((size_t)(b * NREG + ch)) * A2 + p];
}

__device__ __forceinline__ void gtbox(const float* boxes, int b, int m,
                                      float& x1, float& y1, float& x2, float& y2, bool& valid) {
  const float* q = boxes + ((size_t)(b * NM + m)) * 4;
  float cx = q[0], cy = q[1], w = q[2], h = q[3];
  x1 = (cx - w * 0.5f) * 640.f; y1 = (cy - h * 0.5f) * 640.f;
  x2 = (cx + w * 0.5f) * 640.f; y2 = (cy + h * 0.5f) * 640.f;
  valid = (x1 + y1 + x2 + y2) > 0.f;
}

__device__ __forceinline__ float ciou_f(float b1x1, float b1y1, float b1x2, float b1y2,
                                        float b2x1, float b2y1, float b2x2, float b2y2) {
  const float eps = 1e-7f;
  float w1 = b1x2 - b1x1, h1 = b1y2 - b1y1;
  float w2 = b2x2 - b2x1, h2 = b2y2 - b2y1;
  float iw = fmaxf(fminf(b1x2, b2x2) - fmaxf(b1x1, b2x1), 0.f);
  float ih = fmaxf(fminf(b1y2, b2y2) - fmaxf(b1y1, b2y1), 0.f);
  float inter = iw * ih;
  float uni = w1 * h1 + w2 * h2 - inter + eps;
  float iou = inter / uni;
  float cw = fmaxf(b1x2, b2x2) - fminf(b1x1, b2x1);
  float ch = fmaxf(b1y2, b2y2) - fminf(b1y1, b2y1);
  float c2 = cw * cw + ch * ch + eps;
  float dx = b2x1 + b2x2 - b1x1 - b1x2;
  float dy = b2y1 + b2y2 - b1y1 - b1y2;
  float rho2 = (dx * dx + dy * dy) * 0.25f;
  float at = atanf(w2 / (h2 + eps)) - atanf(w1 / (h1 + eps));
  float v = 0.4052847345693511f * at * at;   // 4/pi^2
  float alpha = v / (v - iou + (1.0f + eps));
  return iou - (rho2 / c2 + v * alpha);
}

__device__ __forceinline__ float align_of(float sc, float o) {
  float o2 = o * o, o4 = o2 * o2;
  return sqrtf(sc) * (o2 * o4);  // sc^0.5 * o^6
}

// ---------- kernels ----------

// 1: decode DFL distributions -> pred bboxes (grid units) + per-side max+log(sum exp)
__global__ __launch_bounds__(256) void k_decode(const float* r0, const float* r1, const float* r2,
                                                float4* bb, float4* mls) {
  int t = blockIdx.x * blockDim.x + threadIdx.x;
  if (t >= NB * NA) return;
  int b = t / NA, a = t % NA;
  float ax, ay, s; int lvl, p;
  anch(a, ax, ay, s, lvl, p);
  const float* rg; int HW;
  if (lvl == 0) { rg = r0; HW = A0; }
  else if (lvl == 1) { rg = r1; HW = A1; }
  else { rg = r2; HW = A2; }
  const float* base = rg + ((size_t)b * NREG) * HW + p;
  float dist[4], ml[4];
  for (int sd = 0; sd < 4; ++sd) {
    float x[16]; float mx = -1e30f;
    for (int r = 0; r < 16; ++r) { x[r] = base[(size_t)(sd * 16 + r) * HW]; mx = fmaxf(mx, x[r]); }
    float se = 0.f, wsum = 0.f;
    for (int r = 0; r < 16; ++r) { float e = expf(x[r] - mx); se += e; wsum += e * (float)r; }
    dist[sd] = wsum / se;
    ml[sd] = mx + logf(se);
  }
  bb[t]  = make_float4(ax - dist[0], ay - dist[1], ax + dist[2], ay + dist[3]);
  mls[t] = make_float4(ml[0], ml[1], ml[2], ml[3]);
}

// 2: masked clipped CIoU overlaps (B,M,A)
__global__ __launch_bounds__(256) void k_overlap(const float* boxes, const float4* bb, float* ov) {
  size_t t = (size_t)blockIdx.x * blockDim.x + threadIdx.x;
  if (t >= (size_t)NB * NM * NA) return;
  int a = (int)(t % NA);
  int m = (int)((t / NA) % NM);
  int b = (int)(t / ((size_t)NA * NM));
  float gx1, gy1, gx2, gy2; bool valid;
  gtbox(boxes, b, m, gx1, gy1, gx2, gy2, valid);
  float ax, ay, s; int lvl, p;
  anch(a, ax, ay, s, lvl, p);
  float axp = ax * s, ayp = ay * s;
  float mn = fminf(fminf(axp - gx1, ayp - gy1), fminf(gx2 - axp, gy2 - ayp));
  float o = 0.f;
  if (valid && mn > 1e-9f) {
    float4 pb = bb[(size_t)b * NA + a];
    float c = ciou_f(gx1, gy1, gx2, gy2, pb.x * s, pb.y * s, pb.z * s, pb.w * s);
    o = fmaxf(c, 0.f);
  }
  ov[t] = o;
}

// 3: top-10 per (b,m) with lax.top_k tie semantics; atomic fg count + m-sum
__global__ __launch_bounds__(256) void k_topk(const float* c0, const float* c1, const float* c2,
                                              const int* labels, const float* boxes, const float* ov,
                                              int* fgcnt, int* msum) {
  __shared__ float s_am[NA];
  __shared__ float s_rv[256];
  __shared__ int   s_ri[256];
  int bm = blockIdx.x;
  int b = bm / NM, m = bm % NM;
  int tid = threadIdx.x;
  int lbl = labels[bm]; if (lbl < 0) lbl = 0; if (lbl >= NCC) lbl = NCC - 1;
  float gx1, gy1, gx2, gy2; bool valid;
  gtbox(boxes, b, m, gx1, gy1, gx2, gy2, valid);
  const float* ovrow = ov + (size_t)bm * NA;
  for (int a = tid; a < NA; a += 256) {
    float o = ovrow[a];
    float am = 0.f;
    if (o > 0.f) {
      float x = cls_at(c0, c1, c2, b, lbl, a);
      float sc = 1.f / (1.f + expf(-x));
      am = align_of(sc, o);
    }
    s_am[a] = am;
  }
  __syncthreads();
  for (int k = 0; k < 10; ++k) {
    float bv = -2.f; int bi = 1 << 30;
    for (int a = tid; a < NA; a += 256) {
      float v = s_am[a];
      if (v > bv || (v == bv && a < bi)) { bv = v; bi = a; }
    }
    s_rv[tid] = bv; s_ri[tid] = bi;
    __syncthreads();
    for (int off = 128; off; off >>= 1) {
      if (tid < off) {
        float v = s_rv[tid + off]; int i = s_ri[tid + off];
        if (v > s_rv[tid] || (v == s_rv[tid] && i < s_ri[tid])) { s_rv[tid] = v; s_ri[tid] = i; }
      }
      __syncthreads();
    }
    if (tid == 0) {
      int sel = s_ri[0];
      s_am[sel] = -1.f;
      if (valid) {
        float ax, ay, s; int lvl, p;
        anch(sel, ax, ay, s, lvl, p);
        float axp = ax * s, ayp = ay * s;
        float mn = fminf(fminf(axp - gx1, ayp - gy1), fminf(gx2 - axp, gy2 - ayp));
        if (mn > 1e-9f) {
          atomicAdd(&fgcnt[(size_t)b * NA + sel], 1);
          atomicAdd(&msum[(size_t)b * NA + sel], m);
        }
      }
    }
    __syncthreads();
  }
}

// 4: resolve multi-gt anchors via overlap argmax (first-index ties)
__global__ __launch_bounds__(256) void k_resolve(const float* ov, const int* fgcnt, const int* msum,
                                                 int* assign) {
  int t = blockIdx.x * blockDim.x + threadIdx.x;
  if (t >= NB * NA) return;
  int b = t / NA, a = t % NA;
  int fg = fgcnt[t];
  int asn = -1;
  if (fg == 1) asn = msum[t];
  else if (fg > 1) {
    const float* base = ov + (size_t)b * NM * NA + a;
    float bv = base[0]; int bi = 0;
    for (int m = 1; m < NM; ++m) {
      float v = base[(size_t)m * NA];
      if (v > bv) { bv = v; bi = m; }
    }
    asn = bi;
  }
  assign[t] = asn;
}

// 5: per-gt maxima of align metric & overlap over finally-assigned anchors
__global__ __launch_bounds__(256) void k_posmax(const float* c0, const float* c1, const float* c2,
                                                const int* labels, const float* ov, const int* assign,
                                                float* amv, unsigned* pos_am, unsigned* pos_ov) {
  int t = blockIdx.x * blockDim.x + threadIdx.x;
  if (t >= NB * NA) return;
  int asn = assign[t]; if (asn < 0) return;
  int b = t / NA, a = t % NA;
  float o = ov[((size_t)b * NM + asn) * NA + a];
  float am = 0.f;
  if (o > 0.f) {
    int lbl = labels[b * NM + asn]; if (lbl < 0) lbl = 0; if (lbl >= NCC) lbl = NCC - 1;
    float x = cls_at(c0, c1, c2, b, lbl, a);
    float sc = 1.f / (1.f + expf(-x));
    am = align_of(sc, o);
    atomicMax(&pos_am[b * NM + asn], __float_as_uint(am));
    atomicMax(&pos_ov[b * NM + asn], __float_as_uint(o));
  }
  amv[t] = am;
}

// 6: per-assigned-anchor loss terms -> double accumulators
// acc: 0=splus_sum 1=pos_cls 2=tss 3=iou 4=dfl
__global__ __launch_bounds__(256) void k_posloss(const float* c0, const float* c1, const float* c2,
    const float* r0, const float* r1, const float* r2,
    const float* boxes, const int* labels, const int* assign, const float* amv,
    const float4* bb, const float4* mls, const unsigned* pos_am, const unsigned* pos_ov,
    double* acc) {
  int t = blockIdx.x * blockDim.x + threadIdx.x;
  if (t >= NB * NA) return;
  int asn = assign[t]; if (asn < 0) return;
  int b = t / NA, a = t % NA;
  float pam = __uint_as_float(pos_am[b * NM + asn]);
  float pov = __uint_as_float(pos_ov[b * NM + asn]);
  float norm = amv[t] * pov / (pam + 1e-9f);
  int lbl = labels[b * NM + asn]; if (lbl < 0) lbl = 0; if (lbl >= NCC) lbl = NCC - 1;
  float x = cls_at(c0, c1, c2, b, lbl, a);
  float gx1, gy1, gx2, gy2; bool valid;
  gtbox(boxes, b, asn, gx1, gy1, gx2, gy2, valid);
  float ax, ay, s; int lvl, p;
  anch(a, ax, ay, s, lvl, p);
  float inv_s = 1.f / s;
  float tx1 = gx1 * inv_s, ty1 = gy1 * inv_s, tx2 = gx2 * inv_s, ty2 = gy2 * inv_s;
  float4 pb = bb[t];
  float iou = ciou_f(pb.x, pb.y, pb.z, pb.w, tx1, ty1, tx2, ty2);
  float4 ml = mls[t];
  float tgt[4] = { ax - tx1, ay - ty1, tx2 - ax, ty2 - ay };
  float mlv[4] = { ml.x, ml.y, ml.z, ml.w };
  float dfl = 0.f;
  for (int sd = 0; sd < 4; ++sd) {
    float tv = fminf(fmaxf(tgt[sd], 0.f), 14.99f);
    float tlf = floorf(tv);
    int tl = (int)tlf;
    float wl = (tlf + 1.f) - tv;
    float xtl = reg_at(r0, r1, r2, b, sd * 16 + tl,     lvl, p);
    float xtr = reg_at(r0, r1, r2, b, sd * 16 + tl + 1, lvl, p);
    dfl += -((xtl - mlv[sd]) * wl + (xtr - mlv[sd]) * (1.f - wl));
  }
  dfl *= 0.25f;
  atomicAdd(&acc[2], (double)norm);
  atomicAdd(&acc[1], (double)(norm * x));
  atomicAdd(&acc[3], (double)((1.f - iou) * norm));
  atomicAdd(&acc[4], (double)(dfl * norm));
}

// 7: sum of softplus over all class logits
__global__ __launch_bounds__(256) void k_bce(const float* c0, const float* c1, const float* c2,
                                             double* acc) {
  const size_t N0 = (size_t)NB * NCC * A0;
  const size_t N1 = (size_t)NB * NCC * A1;
  const size_t N2 = (size_t)NB * NCC * A2;
  const size_t NT = N0 + N1 + N2;
  size_t i0 = (size_t)blockIdx.x * blockDim.x + threadIdx.x;
  size_t stride = (size_t)gridDim.x * blockDim.x;
  float lsum = 0.f;
  for (size_t i = i0; i < NT; i += stride) {
    float x;
    if (i < N0) x = c0[i];
    else if (i < N0 + N1) x = c1[i - N0];
    else x = c2[i - N0 - N1];
    lsum += fmaxf(x, 0.f) + log1pf(expf(-fabsf(x)));
  }
  __shared__ float sred[256];
  sred[threadIdx.x] = lsum;
  __syncthreads();
  for (int off = 128; off; off >>= 1) {
    if (threadIdx.x < off) sred[threadIdx.x] += sred[threadIdx.x + off];
    __syncthreads();
  }
  if (threadIdx.x == 0) atomicAdd(&acc[0], (double)sred[0]);
}

// 8: compose outputs
__global__ void k_final(const double* acc, float* out) {
  if (blockIdx.x == 0 && threadIdx.x == 0) {
    double tss = acc[2]; if (tss < 1.0) tss = 1.0;
    double l0 = 0.5 * (acc[0] - acc[1]) / tss;
    double l1 = 7.5 * acc[3] / tss;
    double l2 = 1.5 * acc[4] / tss;
    out[0] = (float)(l0 + l1 + l2);
    out[1] = (float)l0;
    out[2] = (float)l1;
    out[3] = (float)l2;
  }
}

// ---------- launch ----------

extern "C" void kernel_launch(void* const* d_in, const int* in_sizes, int n_in,
                              void* d_out, int out_size, void* d_ws, size_t ws_size,
                              hipStream_t stream) {
  (void)in_sizes; (void)n_in; (void)out_size; (void)ws_size;
  const float* cls0  = (const float*)d_in[0];
  const float* cls1  = (const float*)d_in[1];
  const float* cls2  = (const float*)d_in[2];
  const float* reg0  = (const float*)d_in[3];
  const float* reg1  = (const float*)d_in[4];
  const float* reg2  = (const float*)d_in[5];
  const float* boxes = (const float*)d_in[6];
  const int*   labels = (const int*)d_in[7];
  float* out = (float*)d_out;

  const size_t BA  = (size_t)NB * NA;       // 134400
  const size_t BMA = (size_t)NB * NM * NA;  // 4300800

  float* w      = (float*)d_ws;
  float* bb     = w;                 // BA*4
  float* mls    = bb + BA * 4;       // BA*4
  float* ov     = mls + BA * 4;      // BMA
  float* amv    = ov + BMA;          // BA
  int*   assign = (int*)(amv + BA);  // BA
  int*   fgcnt  = assign + BA;       // BA   -- zeroed
  int*   msum   = fgcnt + BA;        // BA   -- zeroed
  unsigned* pos_am = (unsigned*)(msum + BA);  // NB*NM -- zeroed
  unsigned* pos_ov = pos_am + NB * NM;        // NB*NM -- zeroed
  double* acc   = (double*)(pos_ov + NB * NM); // 8 doubles -- zeroed

  size_t zbytes = (char*)(acc + 8) - (char*)fgcnt;
  hipMemsetAsync(fgcnt, 0, zbytes, stream);

  k_decode<<<525, 256, 0, stream>>>(reg0, reg1, reg2, (float4*)bb, (float4*)mls);
  k_overlap<<<16800, 256, 0, stream>>>(boxes, (const float4*)bb, ov);
  k_topk<<<NB * NM, 256, 0, stream>>>(cls0, cls1, cls2, labels, boxes, ov, fgcnt, msum);
  k_resolve<<<525, 256, 0, stream>>>(ov, fgcnt, msum, assign);
  k_posmax<<<525, 256, 0, stream>>>(cls0, cls1, cls2, labels, ov, assign, amv, pos_am, pos_ov);
  k_posloss<<<525, 256, 0, stream>>>(cls0, cls1, cls2, reg0, reg1, reg2,
                                     boxes, labels, assign, amv,
                                     (const float4*)bb, (const float4*)mls, pos_am, pos_ov, acc);
  k_bce<<<2048, 256, 0, stream>>>(cls0, cls1, cls2, acc);
  k_final<<<1, 64, 0, stream>>>(acc, out);
}

// Round 2
// 172.844 us; speedup vs baseline: 1.1720x; 1.1720x over previous
//
#include <hip/hip_runtime.h>

#define NB 16
#define NM 32
#define NA 8400
#define NCC 80
#define NREG 64
#define A0 6400
#define A1 1600
#define A2 400
#define CAP 768

// ---------- device helpers ----------

__device__ __forceinline__ void anch(int a, float& ax, float& ay, float& s, int& lvl, int& p) {
  if (a < A0)            { lvl = 0; p = a;          s = 8.f;  ax = (float)(p % 80); ay = (float)(p / 80); }
  else if (a < A0 + A1)  { lvl = 1; p = a - A0;     s = 16.f; ax = (float)(p % 40); ay = (float)(p / 40); }
  else                   { lvl = 2; p = a - A0 - A1; s = 32.f; ax = (float)(p % 20); ay = (float)(p / 20); }
}

__device__ __forceinline__ float cls_at(const float* c0, const float* c1, const float* c2,
                                        int b, int ch, int a) {
  if (a < A0)           return c0[((size_t)(b * NCC + ch)) * A0 + a];
  if (a < A0 + A1)      return c1[((size_t)(b * NCC + ch)) * A1 + (a - A0)];
  return c2[((size_t)(b * NCC + ch)) * A2 + (a - A0 - A1)];
}

__device__ __forceinline__ float reg_at(const float* r0, const float* r1, const float* r2,
                                        int b, int ch, int lvl, int p) {
  if (lvl == 0) return r0[((size_t)(b * NREG + ch)) * A0 + p];
  if (lvl == 1) return r1[((size_t)(b * NREG + ch)) * A1 + p];
  return r2[((size_t)(b * NREG + ch)) * A2 + p];
}

__device__ __forceinline__ void gtbox(const float* boxes, int b, int m,
                                      float& x1, float& y1, float& x2, float& y2, bool& valid) {
  const float* q = boxes + ((size_t)(b * NM + m)) * 4;
  float cx = q[0], cy = q[1], w = q[2], h = q[3];
  x1 = (cx - w * 0.5f) * 640.f; y1 = (cy - h * 0.5f) * 640.f;
  x2 = (cx + w * 0.5f) * 640.f; y2 = (cy + h * 0.5f) * 640.f;
  valid = (x1 + y1 + x2 + y2) > 0.f;
}

__device__ __forceinline__ float ciou_f(float b1x1, float b1y1, float b1x2, float b1y2,
                                        float b2x1, float b2y1, float b2x2, float b2y2) {
  const float eps = 1e-7f;
  float w1 = b1x2 - b1x1, h1 = b1y2 - b1y1;
  float w2 = b2x2 - b2x1, h2 = b2y2 - b2y1;
  float iw = fmaxf(fminf(b1x2, b2x2) - fmaxf(b1x1, b2x1), 0.f);
  float ih = fmaxf(fminf(b1y2, b2y2) - fmaxf(b1y1, b2y1), 0.f);
  float inter = iw * ih;
  float uni = w1 * h1 + w2 * h2 - inter + eps;
  float iou = inter / uni;
  float cw = fmaxf(b1x2, b2x2) - fminf(b1x1, b2x1);
  float ch = fmaxf(b1y2, b2y2) - fminf(b1y1, b2y1);
  float c2 = cw * cw + ch * ch + eps;
  float dx = b2x1 + b2x2 - b1x1 - b1x2;
  float dy = b2y1 + b2y2 - b1y1 - b1y2;
  float rho2 = (dx * dx + dy * dy) * 0.25f;
  float at = atanf(w2 / (h2 + eps)) - atanf(w1 / (h1 + eps));
  float v = 0.4052847345693511f * at * at;   // 4/pi^2
  float alpha = v / (v - iou + (1.0f + eps));
  return iou - (rho2 / c2 + v * alpha);
}

__device__ __forceinline__ float align_of(float sc, float o) {
  float o2 = o * o, o4 = o2 * o2;
  return sqrtf(sc) * (o2 * o4);  // sc^0.5 * o^6
}

// ---------- kernels ----------

// 1: decode DFL distributions -> pred bboxes (grid units) + per-side max+log(sum exp)
__global__ __launch_bounds__(256) void k_decode(const float* r0, const float* r1, const float* r2,
                                                float4* bb, float4* mls) {
  int t = blockIdx.x * blockDim.x + threadIdx.x;
  if (t >= NB * NA) return;
  int b = t / NA, a = t % NA;
  float ax, ay, s; int lvl, p;
  anch(a, ax, ay, s, lvl, p);
  const float* rg; int HW;
  if (lvl == 0) { rg = r0; HW = A0; }
  else if (lvl == 1) { rg = r1; HW = A1; }
  else { rg = r2; HW = A2; }
  const float* base = rg + ((size_t)b * NREG) * HW + p;
  float dist[4], ml[4];
  for (int sd = 0; sd < 4; ++sd) {
    float x[16]; float mx = -1e30f;
    for (int r = 0; r < 16; ++r) { x[r] = base[(size_t)(sd * 16 + r) * HW]; mx = fmaxf(mx, x[r]); }
    float se = 0.f, wsum = 0.f;
    for (int r = 0; r < 16; ++r) { float e = expf(x[r] - mx); se += e; wsum += e * (float)r; }
    dist[sd] = wsum / se;
    ml[sd] = mx + logf(se);
  }
  bb[t]  = make_float4(ax - dist[0], ay - dist[1], ax + dist[2], ay + dist[3]);
  mls[t] = make_float4(ml[0], ml[1], ml[2], ml[3]);
}

// 2: build compacted candidate lists per (b,m): masked anchors with align metric
__global__ __launch_bounds__(256) void k_cand(const float* boxes, const int* labels,
                                              const float4* bb,
                                              const float* c0, const float* c1, const float* c2,
                                              int* cand_cnt, float* cand_val, int* cand_idx) {
  int blk = blockIdx.x;           // bm * 33 + chunk
  int bm = blk / 33, chunk = blk % 33;
  int a = chunk * 256 + threadIdx.x;
  int b = bm / NM, m = bm % NM;
  float gx1, gy1, gx2, gy2; bool valid;
  gtbox(boxes, b, m, gx1, gy1, gx2, gy2, valid);
  bool pred = false; float am = 0.f;
  if (a < NA && valid) {
    float ax, ay, s; int lvl, p;
    anch(a, ax, ay, s, lvl, p);
    float axp = ax * s, ayp = ay * s;
    float mn = fminf(fminf(axp - gx1, ayp - gy1), fminf(gx2 - axp, gy2 - ayp));
    if (mn > 1e-9f) {
      pred = true;
      float4 pb = bb[(size_t)b * NA + a];
      float c = ciou_f(gx1, gy1, gx2, gy2, pb.x * s, pb.y * s, pb.z * s, pb.w * s);
      float o = fmaxf(c, 0.f);
      int lbl = labels[bm]; if (lbl < 0) lbl = 0; if (lbl >= NCC) lbl = NCC - 1;
      float x = cls_at(c0, c1, c2, b, lbl, a);
      float sc = 1.f / (1.f + expf(-x));
      am = align_of(sc, o);
    }
  }
  unsigned long long mask = __ballot(pred);
  if (mask) {
    int lane = threadIdx.x & 63;
    int nact = __popcll(mask);
    int leader = __ffsll(mask) - 1;
    int base = 0;
    if (lane == leader) base = atomicAdd(&cand_cnt[bm], nact);
    base = __shfl(base, leader);
    if (pred) {
      int off = base + __popcll(mask & ((1ull << lane) - 1ull));
      if (off < CAP) { cand_val[(size_t)bm * CAP + off] = am; cand_idx[(size_t)bm * CAP + off] = a; }
    }
  }
}

// 3: top-10 per (b,m) over compacted candidates; exact lax.top_k tie semantics
__global__ __launch_bounds__(64) void k_topk2(const int* cand_cnt, const float* cand_val,
                                              const int* cand_idx, int* fgcnt, int* msum) {
  __shared__ float sv[CAP];
  __shared__ int   si[CAP];
  int bm = blockIdx.x;
  int b = bm / NM, m = bm % NM;
  int lane = threadIdx.x;
  int n = cand_cnt[bm]; if (n > CAP) n = CAP;
  if (n == 0) return;
  for (int j = lane; j < n; j += 64) {
    sv[j] = cand_val[(size_t)bm * CAP + j];
    si[j] = cand_idx[(size_t)bm * CAP + j];
  }
  __syncthreads();
  // count positives
  int cnt = 0;
  for (int j = lane; j < n; j += 64) if (sv[j] > 0.f) cnt++;
  for (int o = 32; o; o >>= 1) cnt += __shfl_xor(cnt, o);
  int npos = cnt;

  if (npos > 10) {
    for (int k = 0; k < 10; ++k) {
      float bv = -1.f; int bi = 1 << 30;
      for (int j = lane; j < n; j += 64) {
        float v = sv[j]; int ix = si[j];
        if (v > bv || (v == bv && ix < bi)) { bv = v; bi = ix; }
      }
      for (int o = 32; o; o >>= 1) {
        float v = __shfl_xor(bv, o); int ix = __shfl_xor(bi, o);
        if (v > bv || (v == bv && ix < bi)) { bv = v; bi = ix; }
      }
      for (int j = lane; j < n; j += 64) if (si[j] == bi) sv[j] = -1.f;
      if (lane == 0) {
        atomicAdd(&fgcnt[(size_t)b * NA + bi], 1);
        atomicAdd(&msum[(size_t)b * NA + bi], m);
      }
      __syncthreads();
    }
  } else {
    // all positive candidates are picked
    for (int j = lane; j < n; j += 64) {
      if (sv[j] > 0.f) {
        atomicAdd(&fgcnt[(size_t)b * NA + si[j]], 1);
        atomicAdd(&msum[(size_t)b * NA + si[j]], m);
      }
    }
    // zero-tie fill: zero-am candidate at anchor i picked iff i - pos_below(i) < 10-npos
    // (requires i < 10 — rare corner)
    int need = 10 - npos;
    for (int j = lane; j < n; j += 64) {
      if (sv[j] == 0.f) {
        int i = si[j];
        if (i < 10) {
          int pb = 0;
          for (int q = 0; q < n; ++q) pb += (sv[q] > 0.f && si[q] < i) ? 1 : 0;
          if (i - pb < need) {
            atomicAdd(&fgcnt[(size_t)b * NA + i], 1);
            atomicAdd(&msum[(size_t)b * NA + i], m);
          }
        }
      }
    }
  }
}

// 4: resolve assignment (fg>1 -> overlap argmax, recomputed) + per-gt maxima
__global__ __launch_bounds__(256) void k_resolve(const float* boxes, const int* labels,
                                                 const float4* bb,
                                                 const float* c0, const float* c1, const float* c2,
                                                 const int* fgcnt, const int* msum,
                                                 int* assign, float* amv,
                                                 unsigned* pos_am, unsigned* pos_ov) {
  int t = blockIdx.x * blockDim.x + threadIdx.x;
  if (t >= NB * NA) return;
  int b = t / NA, a = t % NA;
  int fg = fgcnt[t];
  int asn = -1; float o = 0.f;
  if (fg > 0) {
    float ax, ay, s; int lvl, p;
    anch(a, ax, ay, s, lvl, p);
    float axp = ax * s, ayp = ay * s;
    float4 pb = bb[t];
    float px1 = pb.x * s, py1 = pb.y * s, px2 = pb.z * s, py2 = pb.w * s;
    if (fg == 1) {
      asn = msum[t];
      float gx1, gy1, gx2, gy2; bool valid;
      gtbox(boxes, b, asn, gx1, gy1, gx2, gy2, valid);
      o = fmaxf(ciou_f(gx1, gy1, gx2, gy2, px1, py1, px2, py2), 0.f);
    } else {
      float bv = -1e30f; int bi = 0;
      for (int m = 0; m < NM; ++m) {
        float gx1, gy1, gx2, gy2; bool valid;
        gtbox(boxes, b, m, gx1, gy1, gx2, gy2, valid);
        float om = 0.f;
        if (valid) {
          float mn = fminf(fminf(axp - gx1, ayp - gy1), fminf(gx2 - axp, gy2 - ayp));
          if (mn > 1e-9f)
            om = fmaxf(ciou_f(gx1, gy1, gx2, gy2, px1, py1, px2, py2), 0.f);
        }
        if (om > bv) { bv = om; bi = m; }
      }
      asn = bi; o = bv;
    }
    float am = 0.f;
    if (o > 0.f) {
      int lbl = labels[b * NM + asn]; if (lbl < 0) lbl = 0; if (lbl >= NCC) lbl = NCC - 1;
      float x = cls_at(c0, c1, c2, b, lbl, a);
      float sc = 1.f / (1.f + expf(-x));
      am = align_of(sc, o);
      atomicMax(&pos_am[b * NM + asn], __float_as_uint(am));
      atomicMax(&pos_ov[b * NM + asn], __float_as_uint(o));
    }
    amv[t] = am;
  }
  assign[t] = asn;
}

// 5: per-assigned-anchor loss terms -> double accumulators
// acc: 0=splus_sum 1=pos_cls 2=tss 3=iou 4=dfl
__global__ __launch_bounds__(256) void k_posloss(const float* c0, const float* c1, const float* c2,
    const float* r0, const float* r1, const float* r2,
    const float* boxes, const int* labels, const int* assign, const float* amv,
    const float4* bb, const float4* mls, const unsigned* pos_am, const unsigned* pos_ov,
    double* acc) {
  int t = blockIdx.x * blockDim.x + threadIdx.x;
  if (t >= NB * NA) return;
  int asn = assign[t]; if (asn < 0) return;
  int b = t / NA, a = t % NA;
  float pam = __uint_as_float(pos_am[b * NM + asn]);
  float pov = __uint_as_float(pos_ov[b * NM + asn]);
  float norm = amv[t] * pov / (pam + 1e-9f);
  int lbl = labels[b * NM + asn]; if (lbl < 0) lbl = 0; if (lbl >= NCC) lbl = NCC - 1;
  float x = cls_at(c0, c1, c2, b, lbl, a);
  float gx1, gy1, gx2, gy2; bool valid;
  gtbox(boxes, b, asn, gx1, gy1, gx2, gy2, valid);
  float ax, ay, s; int lvl, p;
  anch(a, ax, ay, s, lvl, p);
  float inv_s = 1.f / s;
  float tx1 = gx1 * inv_s, ty1 = gy1 * inv_s, tx2 = gx2 * inv_s, ty2 = gy2 * inv_s;
  float4 pb = bb[t];
  float iou = ciou_f(pb.x, pb.y, pb.z, pb.w, tx1, ty1, tx2, ty2);
  float4 ml = mls[t];
  float tgt[4] = { ax - tx1, ay - ty1, tx2 - ax, ty2 - ay };
  float mlv[4] = { ml.x, ml.y, ml.z, ml.w };
  float dfl = 0.f;
  for (int sd = 0; sd < 4; ++sd) {
    float tv = fminf(fmaxf(tgt[sd], 0.f), 14.99f);
    float tlf = floorf(tv);
    int tl = (int)tlf;
    float wl = (tlf + 1.f) - tv;
    float xtl = reg_at(r0, r1, r2, b, sd * 16 + tl,     lvl, p);
    float xtr = reg_at(r0, r1, r2, b, sd * 16 + tl + 1, lvl, p);
    dfl += -((xtl - mlv[sd]) * wl + (xtr - mlv[sd]) * (1.f - wl));
  }
  dfl *= 0.25f;
  atomicAdd(&acc[2], (double)norm);
  atomicAdd(&acc[1], (double)(norm * x));
  atomicAdd(&acc[3], (double)((1.f - iou) * norm));
  atomicAdd(&acc[4], (double)(dfl * norm));
}

// 6: sum of softplus over all class logits (float4 vectorized)
__global__ __launch_bounds__(256) void k_bce(const float4* c0, const float4* c1, const float4* c2,
                                             double* acc) {
  const size_t N0 = (size_t)NB * NCC * A0 / 4;
  const size_t N1 = (size_t)NB * NCC * A1 / 4;
  const size_t N2 = (size_t)NB * NCC * A2 / 4;
  const size_t NT = N0 + N1 + N2;
  size_t i0 = (size_t)blockIdx.x * blockDim.x + threadIdx.x;
  size_t stride = (size_t)gridDim.x * blockDim.x;
  float lsum = 0.f;
  for (size_t i = i0; i < NT; i += stride) {
    float4 v;
    if (i < N0) v = c0[i];
    else if (i < N0 + N1) v = c1[i - N0];
    else v = c2[i - N0 - N1];
    lsum += fmaxf(v.x, 0.f) + log1pf(expf(-fabsf(v.x)));
    lsum += fmaxf(v.y, 0.f) + log1pf(expf(-fabsf(v.y)));
    lsum += fmaxf(v.z, 0.f) + log1pf(expf(-fabsf(v.z)));
    lsum += fmaxf(v.w, 0.f) + log1pf(expf(-fabsf(v.w)));
  }
  __shared__ float sred[256];
  sred[threadIdx.x] = lsum;
  __syncthreads();
  for (int off = 128; off; off >>= 1) {
    if (threadIdx.x < off) sred[threadIdx.x] += sred[threadIdx.x + off];
    __syncthreads();
  }
  if (threadIdx.x == 0) atomicAdd(&acc[0], (double)sred[0]);
}

// 7: compose outputs
__global__ void k_final(const double* acc, float* out) {
  if (blockIdx.x == 0 && threadIdx.x == 0) {
    double tss = acc[2]; if (tss < 1.0) tss = 1.0;
    double l0 = 0.5 * (acc[0] - acc[1]) / tss;
    double l1 = 7.5 * acc[3] / tss;
    double l2 = 1.5 * acc[4] / tss;
    out[0] = (float)(l0 + l1 + l2);
    out[1] = (float)l0;
    out[2] = (float)l1;
    out[3] = (float)l2;
  }
}

// ---------- launch ----------

extern "C" void kernel_launch(void* const* d_in, const int* in_sizes, int n_in,
                              void* d_out, int out_size, void* d_ws, size_t ws_size,
                              hipStream_t stream) {
  (void)in_sizes; (void)n_in; (void)out_size; (void)ws_size;
  const float* cls0  = (const float*)d_in[0];
  const float* cls1  = (const float*)d_in[1];
  const float* cls2  = (const float*)d_in[2];
  const float* reg0  = (const float*)d_in[3];
  const float* reg1  = (const float*)d_in[4];
  const float* reg2  = (const float*)d_in[5];
  const float* boxes = (const float*)d_in[6];
  const int*   labels = (const int*)d_in[7];
  float* out = (float*)d_out;

  const size_t BA = (size_t)NB * NA;  // 134400
  const int    BM = NB * NM;          // 512

  // zeroed region first (8B-aligned base for doubles)
  char* wsb = (char*)d_ws;
  double*   acc      = (double*)wsb;                       // 8 doubles
  unsigned* pos_am   = (unsigned*)(acc + 8);               // BM
  unsigned* pos_ov   = pos_am + BM;                        // BM
  int*      cand_cnt = (int*)(pos_ov + BM);                // BM
  int*      fgcnt    = cand_cnt + BM;                      // BA
  int*      msum     = fgcnt + BA;                         // BA
  // non-zeroed scratch
  float*    bb       = (float*)(msum + BA);                // BA*4
  float*    mls      = bb + BA * 4;                        // BA*4
  float*    amv      = mls + BA * 4;                       // BA
  int*      assign   = (int*)(amv + BA);                   // BA
  float*    cand_val = (float*)(assign + BA);              // BM*CAP
  int*      cand_idx = (int*)(cand_val + (size_t)BM * CAP);// BM*CAP

  size_t zbytes = (char*)(msum + BA) - (char*)acc;
  hipMemsetAsync(acc, 0, zbytes, stream);

  k_decode<<<525, 256, 0, stream>>>(reg0, reg1, reg2, (float4*)bb, (float4*)mls);
  k_cand<<<BM * 33, 256, 0, stream>>>(boxes, labels, (const float4*)bb,
                                      cls0, cls1, cls2, cand_cnt, cand_val, cand_idx);
  k_topk2<<<BM, 64, 0, stream>>>(cand_cnt, cand_val, cand_idx, fgcnt, msum);
  k_resolve<<<525, 256, 0, stream>>>(boxes, labels, (const float4*)bb, cls0, cls1, cls2,
                                     fgcnt, msum, assign, amv, pos_am, pos_ov);
  k_posloss<<<525, 256, 0, stream>>>(cls0, cls1, cls2, reg0, reg1, reg2,
                                     boxes, labels, assign, amv,
                                     (const float4*)bb, (const float4*)mls, pos_am, pos_ov, acc);
  k_bce<<<2048, 256, 0, stream>>>((const float4*)cls0, (const float4*)cls1, (const float4*)cls2, acc);
  k_final<<<1, 64, 0, stream>>>(acc, out);
}

// Round 3
// 122.672 us; speedup vs baseline: 1.6514x; 1.4090x over previous
//
#include <hip/hip_runtime.h>

#define NB 16
#define NM 32
#define NA 8400
#define NCC 80
#define NREG 64
#define A0 6400
#define A1 1600
#define A2 400
#define CAP 768

// acc layout: padded slots, 16 doubles (128 B) apart to avoid same-cacheline atomics
// slot 0=splus_sum 1=pos_cls 2=tss 3=iou 4=dfl
#define ACC_STRIDE 16
#define ACC_SLOTS 5

// ---------- device helpers ----------

__device__ __forceinline__ void anch(int a, float& ax, float& ay, float& s, int& lvl, int& p) {
  if (a < A0)            { lvl = 0; p = a;          s = 8.f;  ax = (float)(p % 80); ay = (float)(p / 80); }
  else if (a < A0 + A1)  { lvl = 1; p = a - A0;     s = 16.f; ax = (float)(p % 40); ay = (float)(p / 40); }
  else                   { lvl = 2; p = a - A0 - A1; s = 32.f; ax = (float)(p % 20); ay = (float)(p / 20); }
}

__device__ __forceinline__ float cls_at(const float* c0, const float* c1, const float* c2,
                                        int b, int ch, int a) {
  if (a < A0)           return c0[((size_t)(b * NCC + ch)) * A0 + a];
  if (a < A0 + A1)      return c1[((size_t)(b * NCC + ch)) * A1 + (a - A0)];
  return c2[((size_t)(b * NCC + ch)) * A2 + (a - A0 - A1)];
}

__device__ __forceinline__ float reg_at(const float* r0, const float* r1, const float* r2,
                                        int b, int ch, int lvl, int p) {
  if (lvl == 0) return r0[((size_t)(b * NREG + ch)) * A0 + p];
  if (lvl == 1) return r1[((size_t)(b * NREG + ch)) * A1 + p];
  return r2[((size_t)(b * NREG + ch)) * A2 + p];
}

__device__ __forceinline__ void gtbox(const float* boxes, int b, int m,
                                      float& x1, float& y1, float& x2, float& y2, bool& valid) {
  const float* q = boxes + ((size_t)(b * NM + m)) * 4;
  float cx = q[0], cy = q[1], w = q[2], h = q[3];
  x1 = (cx - w * 0.5f) * 640.f; y1 = (cy - h * 0.5f) * 640.f;
  x2 = (cx + w * 0.5f) * 640.f; y2 = (cy + h * 0.5f) * 640.f;
  valid = (x1 + y1 + x2 + y2) > 0.f;
}

__device__ __forceinline__ float ciou_f(float b1x1, float b1y1, float b1x2, float b1y2,
                                        float b2x1, float b2y1, float b2x2, float b2y2) {
  const float eps = 1e-7f;
  float w1 = b1x2 - b1x1, h1 = b1y2 - b1y1;
  float w2 = b2x2 - b2x1, h2 = b2y2 - b2y1;
  float iw = fmaxf(fminf(b1x2, b2x2) - fmaxf(b1x1, b2x1), 0.f);
  float ih = fmaxf(fminf(b1y2, b2y2) - fmaxf(b1y1, b2y1), 0.f);
  float inter = iw * ih;
  float uni = w1 * h1 + w2 * h2 - inter + eps;
  float iou = inter / uni;
  float cw = fmaxf(b1x2, b2x2) - fminf(b1x1, b2x1);
  float ch = fmaxf(b1y2, b2y2) - fminf(b1y1, b2y1);
  float c2 = cw * cw + ch * ch + eps;
  float dx = b2x1 + b2x2 - b1x1 - b1x2;
  float dy = b2y1 + b2y2 - b1y1 - b1y2;
  float rho2 = (dx * dx + dy * dy) * 0.25f;
  float at = atanf(w2 / (h2 + eps)) - atanf(w1 / (h1 + eps));
  float v = 0.4052847345693511f * at * at;   // 4/pi^2
  float alpha = v / (v - iou + (1.0f + eps));
  return iou - (rho2 / c2 + v * alpha);
}

__device__ __forceinline__ float align_of(float sc, float o) {
  float o2 = o * o, o4 = o2 * o2;
  return sqrtf(sc) * (o2 * o4);  // sc^0.5 * o^6
}

// ---------- kernels ----------

// 1: decode DFL distributions -> pred bboxes (grid units) + per-side max+log(sum exp)
__global__ __launch_bounds__(256) void k_decode(const float* r0, const float* r1, const float* r2,
                                                float4* bb, float4* mls) {
  int t = blockIdx.x * blockDim.x + threadIdx.x;
  if (t >= NB * NA) return;
  int b = t / NA, a = t % NA;
  float ax, ay, s; int lvl, p;
  anch(a, ax, ay, s, lvl, p);
  const float* rg; int HW;
  if (lvl == 0) { rg = r0; HW = A0; }
  else if (lvl == 1) { rg = r1; HW = A1; }
  else { rg = r2; HW = A2; }
  const float* base = rg + ((size_t)b * NREG) * HW + p;
  float dist[4], ml[4];
  for (int sd = 0; sd < 4; ++sd) {
    float x[16]; float mx = -1e30f;
    for (int r = 0; r < 16; ++r) { x[r] = base[(size_t)(sd * 16 + r) * HW]; mx = fmaxf(mx, x[r]); }
    float se = 0.f, wsum = 0.f;
    for (int r = 0; r < 16; ++r) { float e = expf(x[r] - mx); se += e; wsum += e * (float)r; }
    dist[sd] = wsum / se;
    ml[sd] = mx + logf(se);
  }
  bb[t]  = make_float4(ax - dist[0], ay - dist[1], ax + dist[2], ay + dist[3]);
  mls[t] = make_float4(ml[0], ml[1], ml[2], ml[3]);
}

// 2: build compacted candidate lists per (b,m): masked anchors with align metric
__global__ __launch_bounds__(256) void k_cand(const float* boxes, const int* labels,
                                              const float4* bb,
                                              const float* c0, const float* c1, const float* c2,
                                              int* cand_cnt, float* cand_val, int* cand_idx) {
  int blk = blockIdx.x;           // bm * 33 + chunk
  int bm = blk / 33, chunk = blk % 33;
  int a = chunk * 256 + threadIdx.x;
  int b = bm / NM, m = bm % NM;
  float gx1, gy1, gx2, gy2; bool valid;
  gtbox(boxes, b, m, gx1, gy1, gx2, gy2, valid);
  bool pred = false; float am = 0.f;
  if (a < NA && valid) {
    float ax, ay, s; int lvl, p;
    anch(a, ax, ay, s, lvl, p);
    float axp = ax * s, ayp = ay * s;
    float mn = fminf(fminf(axp - gx1, ayp - gy1), fminf(gx2 - axp, gy2 - ayp));
    if (mn > 1e-9f) {
      pred = true;
      float4 pb = bb[(size_t)b * NA + a];
      float c = ciou_f(gx1, gy1, gx2, gy2, pb.x * s, pb.y * s, pb.z * s, pb.w * s);
      float o = fmaxf(c, 0.f);
      int lbl = labels[bm]; if (lbl < 0) lbl = 0; if (lbl >= NCC) lbl = NCC - 1;
      float x = cls_at(c0, c1, c2, b, lbl, a);
      float sc = 1.f / (1.f + expf(-x));
      am = align_of(sc, o);
    }
  }
  unsigned long long mask = __ballot(pred);
  if (mask) {
    int lane = threadIdx.x & 63;
    int nact = __popcll(mask);
    int leader = __ffsll(mask) - 1;
    int base = 0;
    if (lane == leader) base = atomicAdd(&cand_cnt[bm], nact);
    base = __shfl(base, leader);
    if (pred) {
      int off = base + __popcll(mask & ((1ull << lane) - 1ull));
      if (off < CAP) { cand_val[(size_t)bm * CAP + off] = am; cand_idx[(size_t)bm * CAP + off] = a; }
    }
  }
}

// 3: top-10 per (b,m) over compacted candidates; exact lax.top_k tie semantics
__global__ __launch_bounds__(64) void k_topk2(const int* cand_cnt, const float* cand_val,
                                              const int* cand_idx, int* fgcnt, int* msum) {
  __shared__ float sv[CAP];
  __shared__ int   si[CAP];
  int bm = blockIdx.x;
  int b = bm / NM, m = bm % NM;
  int lane = threadIdx.x;
  int n = cand_cnt[bm]; if (n > CAP) n = CAP;
  if (n == 0) return;
  for (int j = lane; j < n; j += 64) {
    sv[j] = cand_val[(size_t)bm * CAP + j];
    si[j] = cand_idx[(size_t)bm * CAP + j];
  }
  __syncthreads();
  // count positives
  int cnt = 0;
  for (int j = lane; j < n; j += 64) if (sv[j] > 0.f) cnt++;
  for (int o = 32; o; o >>= 1) cnt += __shfl_xor(cnt, o);
  int npos = cnt;

  if (npos > 10) {
    for (int k = 0; k < 10; ++k) {
      float bv = -1.f; int bi = 1 << 30;
      for (int j = lane; j < n; j += 64) {
        float v = sv[j]; int ix = si[j];
        if (v > bv || (v == bv && ix < bi)) { bv = v; bi = ix; }
      }
      for (int o = 32; o; o >>= 1) {
        float v = __shfl_xor(bv, o); int ix = __shfl_xor(bi, o);
        if (v > bv || (v == bv && ix < bi)) { bv = v; bi = ix; }
      }
      for (int j = lane; j < n; j += 64) if (si[j] == bi) sv[j] = -1.f;
      if (lane == 0) {
        atomicAdd(&fgcnt[(size_t)b * NA + bi], 1);
        atomicAdd(&msum[(size_t)b * NA + bi], m);
      }
      __syncthreads();
    }
  } else {
    // all positive candidates are picked
    for (int j = lane; j < n; j += 64) {
      if (sv[j] > 0.f) {
        atomicAdd(&fgcnt[(size_t)b * NA + si[j]], 1);
        atomicAdd(&msum[(size_t)b * NA + si[j]], m);
      }
    }
    // zero-tie fill: zero-am candidate at anchor i picked iff i - pos_below(i) < 10-npos
    // (requires i < 10 — rare corner)
    int need = 10 - npos;
    for (int j = lane; j < n; j += 64) {
      if (sv[j] == 0.f) {
        int i = si[j];
        if (i < 10) {
          int pb = 0;
          for (int q = 0; q < n; ++q) pb += (sv[q] > 0.f && si[q] < i) ? 1 : 0;
          if (i - pb < need) {
            atomicAdd(&fgcnt[(size_t)b * NA + i], 1);
            atomicAdd(&msum[(size_t)b * NA + i], m);
          }
        }
      }
    }
  }
}

// 4: resolve assignment (fg>1 -> overlap argmax, recomputed) + per-gt maxima
__global__ __launch_bounds__(256) void k_resolve(const float* boxes, const int* labels,
                                                 const float4* bb,
                                                 const float* c0, const float* c1, const float* c2,
                                                 const int* fgcnt, const int* msum,
                                                 int* assign, float* amv,
                                                 unsigned* pos_am, unsigned* pos_ov) {
  int t = blockIdx.x * blockDim.x + threadIdx.x;
  if (t >= NB * NA) return;
  int b = t / NA, a = t % NA;
  int fg = fgcnt[t];
  int asn = -1; float o = 0.f;
  if (fg > 0) {
    float ax, ay, s; int lvl, p;
    anch(a, ax, ay, s, lvl, p);
    float axp = ax * s, ayp = ay * s;
    float4 pb = bb[t];
    float px1 = pb.x * s, py1 = pb.y * s, px2 = pb.z * s, py2 = pb.w * s;
    if (fg == 1) {
      asn = msum[t];
      float gx1, gy1, gx2, gy2; bool valid;
      gtbox(boxes, b, asn, gx1, gy1, gx2, gy2, valid);
      o = fmaxf(ciou_f(gx1, gy1, gx2, gy2, px1, py1, px2, py2), 0.f);
    } else {
      float bv = -1e30f; int bi = 0;
      for (int m = 0; m < NM; ++m) {
        float gx1, gy1, gx2, gy2; bool valid;
        gtbox(boxes, b, m, gx1, gy1, gx2, gy2, valid);
        float om = 0.f;
        if (valid) {
          float mn = fminf(fminf(axp - gx1, ayp - gy1), fminf(gx2 - axp, gy2 - ayp));
          if (mn > 1e-9f)
            om = fmaxf(ciou_f(gx1, gy1, gx2, gy2, px1, py1, px2, py2), 0.f);
        }
        if (om > bv) { bv = om; bi = m; }
      }
      asn = bi; o = bv;
    }
    float am = 0.f;
    if (o > 0.f) {
      int lbl = labels[b * NM + asn]; if (lbl < 0) lbl = 0; if (lbl >= NCC) lbl = NCC - 1;
      float x = cls_at(c0, c1, c2, b, lbl, a);
      float sc = 1.f / (1.f + expf(-x));
      am = align_of(sc, o);
      atomicMax(&pos_am[b * NM + asn], __float_as_uint(am));
      atomicMax(&pos_ov[b * NM + asn], __float_as_uint(o));
    }
    amv[t] = am;
  }
  assign[t] = asn;
}

// 5: per-assigned-anchor loss terms -> block-reduced, one atomic per term per block
__global__ __launch_bounds__(256) void k_posloss(const float* c0, const float* c1, const float* c2,
    const float* r0, const float* r1, const float* r2,
    const float* boxes, const int* labels, const int* assign, const float* amv,
    const float4* bb, const float4* mls, const unsigned* pos_am, const unsigned* pos_ov,
    double* acc) {
  int t = blockIdx.x * blockDim.x + threadIdx.x;
  double t_norm = 0.0, t_x = 0.0, t_iou = 0.0, t_dfl = 0.0;
  int asn = (t < NB * NA) ? assign[t] : -1;
  if (asn >= 0) {
    int b = t / NA, a = t % NA;
    float pam = __uint_as_float(pos_am[b * NM + asn]);
    float pov = __uint_as_float(pos_ov[b * NM + asn]);
    float norm = amv[t] * pov / (pam + 1e-9f);
    int lbl = labels[b * NM + asn]; if (lbl < 0) lbl = 0; if (lbl >= NCC) lbl = NCC - 1;
    float x = cls_at(c0, c1, c2, b, lbl, a);
    float gx1, gy1, gx2, gy2; bool valid;
    gtbox(boxes, b, asn, gx1, gy1, gx2, gy2, valid);
    float ax, ay, s; int lvl, p;
    anch(a, ax, ay, s, lvl, p);
    float inv_s = 1.f / s;
    float tx1 = gx1 * inv_s, ty1 = gy1 * inv_s, tx2 = gx2 * inv_s, ty2 = gy2 * inv_s;
    float4 pb = bb[t];
    float iou = ciou_f(pb.x, pb.y, pb.z, pb.w, tx1, ty1, tx2, ty2);
    float4 ml = mls[t];
    float tgt[4] = { ax - tx1, ay - ty1, tx2 - ax, ty2 - ay };
    float mlv[4] = { ml.x, ml.y, ml.z, ml.w };
    float dfl = 0.f;
    for (int sd = 0; sd < 4; ++sd) {
      float tv = fminf(fmaxf(tgt[sd], 0.f), 14.99f);
      float tlf = floorf(tv);
      int tl = (int)tlf;
      float wl = (tlf + 1.f) - tv;
      float xtl = reg_at(r0, r1, r2, b, sd * 16 + tl,     lvl, p);
      float xtr = reg_at(r0, r1, r2, b, sd * 16 + tl + 1, lvl, p);
      dfl += -((xtl - mlv[sd]) * wl + (xtr - mlv[sd]) * (1.f - wl));
    }
    dfl *= 0.25f;
    t_norm = (double)norm;
    t_x    = (double)(norm * x);
    t_iou  = (double)((1.f - iou) * norm);
    t_dfl  = (double)(dfl * norm);
  }
  __shared__ double sred[256];
  double vals[4] = { t_norm, t_x, t_iou, t_dfl };
  const int slots[4] = { 2, 1, 3, 4 };
  for (int q = 0; q < 4; ++q) {
    sred[threadIdx.x] = vals[q];
    __syncthreads();
    for (int off = 128; off; off >>= 1) {
      if (threadIdx.x < off) sred[threadIdx.x] += sred[threadIdx.x + off];
      __syncthreads();
    }
    if (threadIdx.x == 0 && sred[0] != 0.0)
      atomicAdd(&acc[slots[q] * ACC_STRIDE], sred[0]);
    __syncthreads();
  }
}

// 6: sum of softplus over all class logits (float4 vectorized)
__global__ __launch_bounds__(256) void k_bce(const float4* c0, const float4* c1, const float4* c2,
                                             double* acc) {
  const size_t N0 = (size_t)NB * NCC * A0 / 4;
  const size_t N1 = (size_t)NB * NCC * A1 / 4;
  const size_t N2 = (size_t)NB * NCC * A2 / 4;
  const size_t NT = N0 + N1 + N2;
  size_t i0 = (size_t)blockIdx.x * blockDim.x + threadIdx.x;
  size_t stride = (size_t)gridDim.x * blockDim.x;
  float lsum = 0.f;
  for (size_t i = i0; i < NT; i += stride) {
    float4 v;
    if (i < N0) v = c0[i];
    else if (i < N0 + N1) v = c1[i - N0];
    else v = c2[i - N0 - N1];
    lsum += fmaxf(v.x, 0.f) + log1pf(expf(-fabsf(v.x)));
    lsum += fmaxf(v.y, 0.f) + log1pf(expf(-fabsf(v.y)));
    lsum += fmaxf(v.z, 0.f) + log1pf(expf(-fabsf(v.z)));
    lsum += fmaxf(v.w, 0.f) + log1pf(expf(-fabsf(v.w)));
  }
  __shared__ float sred[256];
  sred[threadIdx.x] = lsum;
  __syncthreads();
  for (int off = 128; off; off >>= 1) {
    if (threadIdx.x < off) sred[threadIdx.x] += sred[threadIdx.x + off];
    __syncthreads();
  }
  if (threadIdx.x == 0) atomicAdd(&acc[0], (double)sred[0]);
}

// 7: compose outputs
__global__ void k_final(const double* acc, float* out) {
  if (blockIdx.x == 0 && threadIdx.x == 0) {
    double tss = acc[2 * ACC_STRIDE]; if (tss < 1.0) tss = 1.0;
    double l0 = 0.5 * (acc[0] - acc[1 * ACC_STRIDE]) / tss;
    double l1 = 7.5 * acc[3 * ACC_STRIDE] / tss;
    double l2 = 1.5 * acc[4 * ACC_STRIDE] / tss;
    out[0] = (float)(l0 + l1 + l2);
    out[1] = (float)l0;
    out[2] = (float)l1;
    out[3] = (float)l2;
  }
}

// ---------- launch ----------

extern "C" void kernel_launch(void* const* d_in, const int* in_sizes, int n_in,
                              void* d_out, int out_size, void* d_ws, size_t ws_size,
                              hipStream_t stream) {
  (void)in_sizes; (void)n_in; (void)out_size; (void)ws_size;
  const float* cls0  = (const float*)d_in[0];
  const float* cls1  = (const float*)d_in[1];
  const float* cls2  = (const float*)d_in[2];
  const float* reg0  = (const float*)d_in[3];
  const float* reg1  = (const float*)d_in[4];
  const float* reg2  = (const float*)d_in[5];
  const float* boxes = (const float*)d_in[6];
  const int*   labels = (const int*)d_in[7];
  float* out = (float*)d_out;

  const size_t BA = (size_t)NB * NA;  // 134400
  const int    BM = NB * NM;          // 512

  // zeroed region first (8B-aligned base for doubles)
  char* wsb = (char*)d_ws;
  double*   acc      = (double*)wsb;                       // ACC_SLOTS*ACC_STRIDE doubles
  unsigned* pos_am   = (unsigned*)(acc + ACC_SLOTS * ACC_STRIDE); // BM
  unsigned* pos_ov   = pos_am + BM;                        // BM
  int*      cand_cnt = (int*)(pos_ov + BM);                // BM
  int*      fgcnt    = cand_cnt + BM;                      // BA
  int*      msum     = fgcnt + BA;                         // BA
  // non-zeroed scratch
  float*    bb       = (float*)(msum + BA);                // BA*4
  float*    mls      = bb + BA * 4;                        // BA*4
  float*    amv      = mls + BA * 4;                       // BA
  int*      assign   = (int*)(amv + BA);                   // BA
  float*    cand_val = (float*)(assign + BA);              // BM*CAP
  int*      cand_idx = (int*)(cand_val + (size_t)BM * CAP);// BM*CAP

  size_t zbytes = (char*)(msum + BA) - (char*)acc;
  hipMemsetAsync(acc, 0, zbytes, stream);

  k_decode<<<525, 256, 0, stream>>>(reg0, reg1, reg2, (float4*)bb, (float4*)mls);
  k_cand<<<BM * 33, 256, 0, stream>>>(boxes, labels, (const float4*)bb,
                                      cls0, cls1, cls2, cand_cnt, cand_val, cand_idx);
  k_topk2<<<BM, 64, 0, stream>>>(cand_cnt, cand_val, cand_idx, fgcnt, msum);
  k_resolve<<<525, 256, 0, stream>>>(boxes, labels, (const float4*)bb, cls0, cls1, cls2,
                                     fgcnt, msum, assign, amv, pos_am, pos_ov);
  k_posloss<<<525, 256, 0, stream>>>(cls0, cls1, cls2, reg0, reg1, reg2,
                                     boxes, labels, assign, amv,
                                     (const float4*)bb, (const float4*)mls, pos_am, pos_ov, acc);
  k_bce<<<2048, 256, 0, stream>>>((const float4*)cls0, (const float4*)cls1, (const float4*)cls2, acc);
  k_final<<<1, 64, 0, stream>>>(acc, out);
}

// Round 4
// 118.295 us; speedup vs baseline: 1.7125x; 1.0370x over previous
//
#include <hip/hip_runtime.h>

#define NB 16
#define NM 32
#define NA 8400
#define NCC 80
#define NREG 64
#define A0 6400
#define A1 1600
#define A2 400
#define CAP 768

// acc layout: padded slots, 16 doubles (128 B) apart to avoid same-cacheline atomics
// slot 0=splus_sum 1=pos_cls 2=tss 3=iou 4=dfl
#define ACC_STRIDE 16
#define ACC_SLOTS 5

// ---------- device helpers ----------

__device__ __forceinline__ void anch(int a, float& ax, float& ay, float& s, int& lvl, int& p) {
  if (a < A0)            { lvl = 0; p = a;          s = 8.f;  ax = (float)(p % 80); ay = (float)(p / 80); }
  else if (a < A0 + A1)  { lvl = 1; p = a - A0;     s = 16.f; ax = (float)(p % 40); ay = (float)(p / 40); }
  else                   { lvl = 2; p = a - A0 - A1; s = 32.f; ax = (float)(p % 20); ay = (float)(p / 20); }
}

__device__ __forceinline__ float cls_at(const float* c0, const float* c1, const float* c2,
                                        int b, int ch, int a) {
  if (a < A0)           return c0[((size_t)(b * NCC + ch)) * A0 + a];
  if (a < A0 + A1)      return c1[((size_t)(b * NCC + ch)) * A1 + (a - A0)];
  return c2[((size_t)(b * NCC + ch)) * A2 + (a - A0 - A1)];
}

__device__ __forceinline__ float reg_at(const float* r0, const float* r1, const float* r2,
                                        int b, int ch, int lvl, int p) {
  if (lvl == 0) return r0[((size_t)(b * NREG + ch)) * A0 + p];
  if (lvl == 1) return r1[((size_t)(b * NREG + ch)) * A1 + p];
  return r2[((size_t)(b * NREG + ch)) * A2 + p];
}

__device__ __forceinline__ void gtbox(const float* boxes, int b, int m,
                                      float& x1, float& y1, float& x2, float& y2, bool& valid) {
  const float* q = boxes + ((size_t)(b * NM + m)) * 4;
  float cx = q[0], cy = q[1], w = q[2], h = q[3];
  x1 = (cx - w * 0.5f) * 640.f; y1 = (cy - h * 0.5f) * 640.f;
  x2 = (cx + w * 0.5f) * 640.f; y2 = (cy + h * 0.5f) * 640.f;
  valid = (x1 + y1 + x2 + y2) > 0.f;
}

__device__ __forceinline__ float ciou_f(float b1x1, float b1y1, float b1x2, float b1y2,
                                        float b2x1, float b2y1, float b2x2, float b2y2) {
  const float eps = 1e-7f;
  float w1 = b1x2 - b1x1, h1 = b1y2 - b1y1;
  float w2 = b2x2 - b2x1, h2 = b2y2 - b2y1;
  float iw = fmaxf(fminf(b1x2, b2x2) - fmaxf(b1x1, b2x1), 0.f);
  float ih = fmaxf(fminf(b1y2, b2y2) - fmaxf(b1y1, b2y1), 0.f);
  float inter = iw * ih;
  float uni = w1 * h1 + w2 * h2 - inter + eps;
  float iou = inter / uni;
  float cw = fmaxf(b1x2, b2x2) - fminf(b1x1, b2x1);
  float ch = fmaxf(b1y2, b2y2) - fminf(b1y1, b2y1);
  float c2 = cw * cw + ch * ch + eps;
  float dx = b2x1 + b2x2 - b1x1 - b1x2;
  float dy = b2y1 + b2y2 - b1y1 - b1y2;
  float rho2 = (dx * dx + dy * dy) * 0.25f;
  float at = atanf(w2 / (h2 + eps)) - atanf(w1 / (h1 + eps));
  float v = 0.4052847345693511f * at * at;   // 4/pi^2
  float alpha = v / (v - iou + (1.0f + eps));
  return iou - (rho2 / c2 + v * alpha);
}

__device__ __forceinline__ float align_of(float sc, float o) {
  float o2 = o * o, o4 = o2 * o2;
  return sqrtf(sc) * (o2 * o4);  // sc^0.5 * o^6
}

// fast softplus via native v_exp_f32 / v_log_f32
__device__ __forceinline__ float softplus_fast(float x) {
  float e = __expf(-fabsf(x));
  return fmaxf(x, 0.f) + __logf(1.f + e);
}

// ---------- kernels ----------

// 1: decode DFL distributions -> pred bboxes (grid units) + per-side max+log(sum exp)
__global__ __launch_bounds__(256) void k_decode(const float* r0, const float* r1, const float* r2,
                                                float4* bb, float4* mls) {
  int t = blockIdx.x * blockDim.x + threadIdx.x;
  if (t >= NB * NA) return;
  int b = t / NA, a = t % NA;
  float ax, ay, s; int lvl, p;
  anch(a, ax, ay, s, lvl, p);
  const float* rg; int HW;
  if (lvl == 0) { rg = r0; HW = A0; }
  else if (lvl == 1) { rg = r1; HW = A1; }
  else { rg = r2; HW = A2; }
  const float* base = rg + ((size_t)b * NREG) * HW + p;
  float dist[4], ml[4];
  for (int sd = 0; sd < 4; ++sd) {
    float x[16]; float mx = -1e30f;
    for (int r = 0; r < 16; ++r) { x[r] = base[(size_t)(sd * 16 + r) * HW]; mx = fmaxf(mx, x[r]); }
    float se = 0.f, wsum = 0.f;
    for (int r = 0; r < 16; ++r) { float e = __expf(x[r] - mx); se += e; wsum += e * (float)r; }
    dist[sd] = wsum / se;
    ml[sd] = mx + __logf(se);
  }
  bb[t]  = make_float4(ax - dist[0], ay - dist[1], ax + dist[2], ay + dist[3]);
  mls[t] = make_float4(ml[0], ml[1], ml[2], ml[3]);
}

// 2: build compacted candidate lists per (b,m): masked anchors with align metric
__global__ __launch_bounds__(256) void k_cand(const float* boxes, const int* labels,
                                              const float4* bb,
                                              const float* c0, const float* c1, const float* c2,
                                              int* cand_cnt, float* cand_val, int* cand_idx) {
  int blk = blockIdx.x;           // bm * 33 + chunk
  int bm = blk / 33, chunk = blk % 33;
  int a = chunk * 256 + threadIdx.x;
  int b = bm / NM, m = bm % NM;
  float gx1, gy1, gx2, gy2; bool valid;
  gtbox(boxes, b, m, gx1, gy1, gx2, gy2, valid);
  bool pred = false; float am = 0.f;
  if (a < NA && valid) {
    float ax, ay, s; int lvl, p;
    anch(a, ax, ay, s, lvl, p);
    float axp = ax * s, ayp = ay * s;
    float mn = fminf(fminf(axp - gx1, ayp - gy1), fminf(gx2 - axp, gy2 - ayp));
    if (mn > 1e-9f) {
      pred = true;
      float4 pb = bb[(size_t)b * NA + a];
      float c = ciou_f(gx1, gy1, gx2, gy2, pb.x * s, pb.y * s, pb.z * s, pb.w * s);
      float o = fmaxf(c, 0.f);
      int lbl = labels[bm]; if (lbl < 0) lbl = 0; if (lbl >= NCC) lbl = NCC - 1;
      float x = cls_at(c0, c1, c2, b, lbl, a);
      float sc = 1.f / (1.f + expf(-x));
      am = align_of(sc, o);
    }
  }
  unsigned long long mask = __ballot(pred);
  if (mask) {
    int lane = threadIdx.x & 63;
    int nact = __popcll(mask);
    int leader = __ffsll(mask) - 1;
    int base = 0;
    if (lane == leader) base = atomicAdd(&cand_cnt[bm], nact);
    base = __shfl(base, leader);
    if (pred) {
      int off = base + __popcll(mask & ((1ull << lane) - 1ull));
      if (off < CAP) { cand_val[(size_t)bm * CAP + off] = am; cand_idx[(size_t)bm * CAP + off] = a; }
    }
  }
}

// 3: top-10 per (b,m) over compacted candidates; exact lax.top_k tie semantics
__global__ __launch_bounds__(64) void k_topk2(const int* cand_cnt, const float* cand_val,
                                              const int* cand_idx, int* fgcnt, int* msum) {
  __shared__ float sv[CAP];
  __shared__ int   si[CAP];
  int bm = blockIdx.x;
  int b = bm / NM, m = bm % NM;
  int lane = threadIdx.x;
  int n = cand_cnt[bm]; if (n > CAP) n = CAP;
  if (n == 0) return;
  for (int j = lane; j < n; j += 64) {
    sv[j] = cand_val[(size_t)bm * CAP + j];
    si[j] = cand_idx[(size_t)bm * CAP + j];
  }
  __syncthreads();
  // count positives
  int cnt = 0;
  for (int j = lane; j < n; j += 64) if (sv[j] > 0.f) cnt++;
  for (int o = 32; o; o >>= 1) cnt += __shfl_xor(cnt, o);
  int npos = cnt;

  if (npos > 10) {
    for (int k = 0; k < 10; ++k) {
      float bv = -1.f; int bi = 1 << 30;
      for (int j = lane; j < n; j += 64) {
        float v = sv[j]; int ix = si[j];
        if (v > bv || (v == bv && ix < bi)) { bv = v; bi = ix; }
      }
      for (int o = 32; o; o >>= 1) {
        float v = __shfl_xor(bv, o); int ix = __shfl_xor(bi, o);
        if (v > bv || (v == bv && ix < bi)) { bv = v; bi = ix; }
      }
      for (int j = lane; j < n; j += 64) if (si[j] == bi) sv[j] = -1.f;
      if (lane == 0) {
        atomicAdd(&fgcnt[(size_t)b * NA + bi], 1);
        atomicAdd(&msum[(size_t)b * NA + bi], m);
      }
      __syncthreads();
    }
  } else {
    // all positive candidates are picked
    for (int j = lane; j < n; j += 64) {
      if (sv[j] > 0.f) {
        atomicAdd(&fgcnt[(size_t)b * NA + si[j]], 1);
        atomicAdd(&msum[(size_t)b * NA + si[j]], m);
      }
    }
    // zero-tie fill: zero-am candidate at anchor i picked iff i - pos_below(i) < 10-npos
    // (requires i < 10 — rare corner)
    int need = 10 - npos;
    for (int j = lane; j < n; j += 64) {
      if (sv[j] == 0.f) {
        int i = si[j];
        if (i < 10) {
          int pb = 0;
          for (int q = 0; q < n; ++q) pb += (sv[q] > 0.f && si[q] < i) ? 1 : 0;
          if (i - pb < need) {
            atomicAdd(&fgcnt[(size_t)b * NA + i], 1);
            atomicAdd(&msum[(size_t)b * NA + i], m);
          }
        }
      }
    }
  }
}

// 4: resolve assignment (fg>1 -> overlap argmax, recomputed) + per-gt maxima
__global__ __launch_bounds__(256) void k_resolve(const float* boxes, const int* labels,
                                                 const float4* bb,
                                                 const float* c0, const float* c1, const float* c2,
                                                 const int* fgcnt, const int* msum,
                                                 int* assign, float* amv,
                                                 unsigned* pos_am, unsigned* pos_ov) {
  int t = blockIdx.x * blockDim.x + threadIdx.x;
  if (t >= NB * NA) return;
  int b = t / NA, a = t % NA;
  int fg = fgcnt[t];
  int asn = -1; float o = 0.f;
  if (fg > 0) {
    float ax, ay, s; int lvl, p;
    anch(a, ax, ay, s, lvl, p);
    float axp = ax * s, ayp = ay * s;
    float4 pb = bb[t];
    float px1 = pb.x * s, py1 = pb.y * s, px2 = pb.z * s, py2 = pb.w * s;
    if (fg == 1) {
      asn = msum[t];
      float gx1, gy1, gx2, gy2; bool valid;
      gtbox(boxes, b, asn, gx1, gy1, gx2, gy2, valid);
      o = fmaxf(ciou_f(gx1, gy1, gx2, gy2, px1, py1, px2, py2), 0.f);
    } else {
      float bv = -1e30f; int bi = 0;
      for (int m = 0; m < NM; ++m) {
        float gx1, gy1, gx2, gy2; bool valid;
        gtbox(boxes, b, m, gx1, gy1, gx2, gy2, valid);
        float om = 0.f;
        if (valid) {
          float mn = fminf(fminf(axp - gx1, ayp - gy1), fminf(gx2 - axp, gy2 - ayp));
          if (mn > 1e-9f)
            om = fmaxf(ciou_f(gx1, gy1, gx2, gy2, px1, py1, px2, py2), 0.f);
        }
        if (om > bv) { bv = om; bi = m; }
      }
      asn = bi; o = bv;
    }
    float am = 0.f;
    if (o > 0.f) {
      int lbl = labels[b * NM + asn]; if (lbl < 0) lbl = 0; if (lbl >= NCC) lbl = NCC - 1;
      float x = cls_at(c0, c1, c2, b, lbl, a);
      float sc = 1.f / (1.f + expf(-x));
      am = align_of(sc, o);
      atomicMax(&pos_am[b * NM + asn], __float_as_uint(am));
      atomicMax(&pos_ov[b * NM + asn], __float_as_uint(o));
    }
    amv[t] = am;
  }
  assign[t] = asn;
}

// 5: per-assigned-anchor loss terms -> block-reduced, one atomic per term per block
__global__ __launch_bounds__(256) void k_posloss(const float* c0, const float* c1, const float* c2,
    const float* r0, const float* r1, const float* r2,
    const float* boxes, const int* labels, const int* assign, const float* amv,
    const float4* bb, const float4* mls, const unsigned* pos_am, const unsigned* pos_ov,
    double* acc) {
  int t = blockIdx.x * blockDim.x + threadIdx.x;
  double t_norm = 0.0, t_x = 0.0, t_iou = 0.0, t_dfl = 0.0;
  int asn = (t < NB * NA) ? assign[t] : -1;
  if (asn >= 0) {
    int b = t / NA, a = t % NA;
    float pam = __uint_as_float(pos_am[b * NM + asn]);
    float pov = __uint_as_float(pos_ov[b * NM + asn]);
    float norm = amv[t] * pov / (pam + 1e-9f);
    int lbl = labels[b * NM + asn]; if (lbl < 0) lbl = 0; if (lbl >= NCC) lbl = NCC - 1;
    float x = cls_at(c0, c1, c2, b, lbl, a);
    float gx1, gy1, gx2, gy2; bool valid;
    gtbox(boxes, b, asn, gx1, gy1, gx2, gy2, valid);
    float ax, ay, s; int lvl, p;
    anch(a, ax, ay, s, lvl, p);
    float inv_s = 1.f / s;
    float tx1 = gx1 * inv_s, ty1 = gy1 * inv_s, tx2 = gx2 * inv_s, ty2 = gy2 * inv_s;
    float4 pb = bb[t];
    float iou = ciou_f(pb.x, pb.y, pb.z, pb.w, tx1, ty1, tx2, ty2);
    float4 ml = mls[t];
    float tgt[4] = { ax - tx1, ay - ty1, tx2 - ax, ty2 - ay };
    float mlv[4] = { ml.x, ml.y, ml.z, ml.w };
    float dfl = 0.f;
    for (int sd = 0; sd < 4; ++sd) {
      float tv = fminf(fmaxf(tgt[sd], 0.f), 14.99f);
      float tlf = floorf(tv);
      int tl = (int)tlf;
      float wl = (tlf + 1.f) - tv;
      float xtl = reg_at(r0, r1, r2, b, sd * 16 + tl,     lvl, p);
      float xtr = reg_at(r0, r1, r2, b, sd * 16 + tl + 1, lvl, p);
      dfl += -((xtl - mlv[sd]) * wl + (xtr - mlv[sd]) * (1.f - wl));
    }
    dfl *= 0.25f;
    t_norm = (double)norm;
    t_x    = (double)(norm * x);
    t_iou  = (double)((1.f - iou) * norm);
    t_dfl  = (double)(dfl * norm);
  }
  __shared__ double sred[256];
  double vals[4] = { t_norm, t_x, t_iou, t_dfl };
  const int slots[4] = { 2, 1, 3, 4 };
  for (int q = 0; q < 4; ++q) {
    sred[threadIdx.x] = vals[q];
    __syncthreads();
    for (int off = 128; off; off >>= 1) {
      if (threadIdx.x < off) sred[threadIdx.x] += sred[threadIdx.x + off];
      __syncthreads();
    }
    if (threadIdx.x == 0 && sred[0] != 0.0)
      atomicAdd(&acc[slots[q] * ACC_STRIDE], sred[0]);
    __syncthreads();
  }
}

// 6: sum of softplus over all class logits (float4 vectorized, fast transcendentals)
__global__ __launch_bounds__(256) void k_bce(const float4* c0, const float4* c1, const float4* c2,
                                             double* acc) {
  const size_t N0 = (size_t)NB * NCC * A0 / 4;
  const size_t N1 = (size_t)NB * NCC * A1 / 4;
  const size_t N2 = (size_t)NB * NCC * A2 / 4;
  const size_t NT = N0 + N1 + N2;
  size_t i0 = (size_t)blockIdx.x * blockDim.x + threadIdx.x;
  size_t stride = (size_t)gridDim.x * blockDim.x;
  float s0 = 0.f, s1 = 0.f;
  for (size_t i = i0; i < NT; i += stride) {
    float4 v;
    if (i < N0) v = c0[i];
    else if (i < N0 + N1) v = c1[i - N0];
    else v = c2[i - N0 - N1];
    s0 += softplus_fast(v.x) + softplus_fast(v.z);
    s1 += softplus_fast(v.y) + softplus_fast(v.w);
  }
  float lsum = s0 + s1;
  __shared__ float sred[256];
  sred[threadIdx.x] = lsum;
  __syncthreads();
  for (int off = 128; off; off >>= 1) {
    if (threadIdx.x < off) sred[threadIdx.x] += sred[threadIdx.x + off];
    __syncthreads();
  }
  if (threadIdx.x == 0) atomicAdd(&acc[0], (double)sred[0]);
}

// 7: compose outputs
__global__ void k_final(const double* acc, float* out) {
  if (blockIdx.x == 0 && threadIdx.x == 0) {
    double tss = acc[2 * ACC_STRIDE]; if (tss < 1.0) tss = 1.0;
    double l0 = 0.5 * (acc[0] - acc[1 * ACC_STRIDE]) / tss;
    double l1 = 7.5 * acc[3 * ACC_STRIDE] / tss;
    double l2 = 1.5 * acc[4 * ACC_STRIDE] / tss;
    out[0] = (float)(l0 + l1 + l2);
    out[1] = (float)l0;
    out[2] = (float)l1;
    out[3] = (float)l2;
  }
}

// ---------- launch ----------

extern "C" void kernel_launch(void* const* d_in, const int* in_sizes, int n_in,
                              void* d_out, int out_size, void* d_ws, size_t ws_size,
                              hipStream_t stream) {
  (void)in_sizes; (void)n_in; (void)out_size; (void)ws_size;
  const float* cls0  = (const float*)d_in[0];
  const float* cls1  = (const float*)d_in[1];
  const float* cls2  = (const float*)d_in[2];
  const float* reg0  = (const float*)d_in[3];
  const float* reg1  = (const float*)d_in[4];
  const float* reg2  = (const float*)d_in[5];
  const float* boxes = (const float*)d_in[6];
  const int*   labels = (const int*)d_in[7];
  float* out = (float*)d_out;

  const size_t BA = (size_t)NB * NA;  // 134400
  const int    BM = NB * NM;          // 512

  // zeroed region first (8B-aligned base for doubles)
  char* wsb = (char*)d_ws;
  double*   acc      = (double*)wsb;                       // ACC_SLOTS*ACC_STRIDE doubles
  unsigned* pos_am   = (unsigned*)(acc + ACC_SLOTS * ACC_STRIDE); // BM
  unsigned* pos_ov   = pos_am + BM;                        // BM
  int*      cand_cnt = (int*)(pos_ov + BM);                // BM
  int*      fgcnt    = cand_cnt + BM;                      // BA
  int*      msum     = fgcnt + BA;                         // BA
  // non-zeroed scratch
  float*    bb       = (float*)(msum + BA);                // BA*4
  float*    mls      = bb + BA * 4;                        // BA*4
  float*    amv      = mls + BA * 4;                       // BA
  int*      assign   = (int*)(amv + BA);                   // BA
  float*    cand_val = (float*)(assign + BA);              // BM*CAP
  int*      cand_idx = (int*)(cand_val + (size_t)BM * CAP);// BM*CAP

  size_t zbytes = (char*)(msum + BA) - (char*)acc;
  hipMemsetAsync(acc, 0, zbytes, stream);

  k_decode<<<525, 256, 0, stream>>>(reg0, reg1, reg2, (float4*)bb, (float4*)mls);
  k_cand<<<BM * 33, 256, 0, stream>>>(boxes, labels, (const float4*)bb,
                                      cls0, cls1, cls2, cand_cnt, cand_val, cand_idx);
  k_topk2<<<BM, 64, 0, stream>>>(cand_cnt, cand_val, cand_idx, fgcnt, msum);
  k_resolve<<<525, 256, 0, stream>>>(boxes, labels, (const float4*)bb, cls0, cls1, cls2,
                                     fgcnt, msum, assign, amv, pos_am, pos_ov);
  k_posloss<<<525, 256, 0, stream>>>(cls0, cls1, cls2, reg0, reg1, reg2,
                                     boxes, labels, assign, amv,
                                     (const float4*)bb, (const float4*)mls, pos_am, pos_ov, acc);
  k_bce<<<2048, 256, 0, stream>>>((const float4*)cls0, (const float4*)cls1, (const float4*)cls2, acc);
  k_final<<<1, 64, 0, stream>>>(acc, out);
}

// Round 5
// 113.350 us; speedup vs baseline: 1.7872x; 1.0436x over previous
//
#include <hip/hip_runtime.h>

#define NB 16
#define NM 32
#define NA 8400
#define NCC 80
#define NREG 64
#define A0 6400
#define A1 1600
#define A2 400
#define CAP 768

// acc layout: padded slots, 16 doubles (128 B) apart to avoid same-cacheline atomics
// slot 0=splus_sum 1=pos_cls 2=tss 3=iou 4=dfl
#define ACC_STRIDE 16
#define ACC_SLOTS 5

// ---------- device helpers ----------

__device__ __forceinline__ void anch(int a, float& ax, float& ay, float& s, int& lvl, int& p) {
  if (a < A0)            { lvl = 0; p = a;          s = 8.f;  ax = (float)(p % 80); ay = (float)(p / 80); }
  else if (a < A0 + A1)  { lvl = 1; p = a - A0;     s = 16.f; ax = (float)(p % 40); ay = (float)(p / 40); }
  else                   { lvl = 2; p = a - A0 - A1; s = 32.f; ax = (float)(p % 20); ay = (float)(p / 20); }
}

__device__ __forceinline__ float cls_at(const float* c0, const float* c1, const float* c2,
                                        int b, int ch, int a) {
  if (a < A0)           return c0[((size_t)(b * NCC + ch)) * A0 + a];
  if (a < A0 + A1)      return c1[((size_t)(b * NCC + ch)) * A1 + (a - A0)];
  return c2[((size_t)(b * NCC + ch)) * A2 + (a - A0 - A1)];
}

__device__ __forceinline__ float reg_at(const float* r0, const float* r1, const float* r2,
                                        int b, int ch, int lvl, int p) {
  if (lvl == 0) return r0[((size_t)(b * NREG + ch)) * A0 + p];
  if (lvl == 1) return r1[((size_t)(b * NREG + ch)) * A1 + p];
  return r2[((size_t)(b * NREG + ch)) * A2 + p];
}

__device__ __forceinline__ void gtbox(const float* boxes, int b, int m,
                                      float& x1, float& y1, float& x2, float& y2, bool& valid) {
  const float* q = boxes + ((size_t)(b * NM + m)) * 4;
  float cx = q[0], cy = q[1], w = q[2], h = q[3];
  x1 = (cx - w * 0.5f) * 640.f; y1 = (cy - h * 0.5f) * 640.f;
  x2 = (cx + w * 0.5f) * 640.f; y2 = (cy + h * 0.5f) * 640.f;
  valid = (x1 + y1 + x2 + y2) > 0.f;
}

__device__ __forceinline__ float ciou_f(float b1x1, float b1y1, float b1x2, float b1y2,
                                        float b2x1, float b2y1, float b2x2, float b2y2) {
  const float eps = 1e-7f;
  float w1 = b1x2 - b1x1, h1 = b1y2 - b1y1;
  float w2 = b2x2 - b2x1, h2 = b2y2 - b2y1;
  float iw = fmaxf(fminf(b1x2, b2x2) - fmaxf(b1x1, b2x1), 0.f);
  float ih = fmaxf(fminf(b1y2, b2y2) - fmaxf(b1y1, b2y1), 0.f);
  float inter = iw * ih;
  float uni = w1 * h1 + w2 * h2 - inter + eps;
  float iou = inter / uni;
  float cw = fmaxf(b1x2, b2x2) - fminf(b1x1, b2x1);
  float ch = fmaxf(b1y2, b2y2) - fminf(b1y1, b2y1);
  float c2 = cw * cw + ch * ch + eps;
  float dx = b2x1 + b2x2 - b1x1 - b1x2;
  float dy = b2y1 + b2y2 - b1y1 - b1y2;
  float rho2 = (dx * dx + dy * dy) * 0.25f;
  float at = atanf(w2 / (h2 + eps)) - atanf(w1 / (h1 + eps));
  float v = 0.4052847345693511f * at * at;   // 4/pi^2
  float alpha = v / (v - iou + (1.0f + eps));
  return iou - (rho2 / c2 + v * alpha);
}

__device__ __forceinline__ float align_of(float sc, float o) {
  float o2 = o * o, o4 = o2 * o2;
  return sqrtf(sc) * (o2 * o4);  // sc^0.5 * o^6
}

// fast softplus via native v_exp_f32 / v_log_f32
__device__ __forceinline__ float softplus_fast(float x) {
  float e = __expf(-fabsf(x));
  return fmaxf(x, 0.f) + __logf(1.f + e);
}

// ---------- kernels ----------

// 1: decode DFL -> pred bboxes + per-side max+log(sum exp); also zeroes all
//    atomically-updated scratch (replaces the pathologically slow runtime fill)
__global__ __launch_bounds__(256) void k_decode(const float* r0, const float* r1, const float* r2,
                                                float4* bb, float4* mls,
                                                int* fgcnt, int* msum, int* cand_cnt,
                                                unsigned* pos_am, unsigned* pos_ov, double* acc) {
  int t = blockIdx.x * blockDim.x + threadIdx.x;
  if (t >= NB * NA) return;
  // zero scratch consumed by later kernels (stream-ordered)
  fgcnt[t] = 0;
  msum[t] = 0;
  if (t < NB * NM) { cand_cnt[t] = 0; pos_am[t] = 0u; pos_ov[t] = 0u; }
  if (t < ACC_SLOTS * ACC_STRIDE) acc[t] = 0.0;

  int b = t / NA, a = t % NA;
  float ax, ay, s; int lvl, p;
  anch(a, ax, ay, s, lvl, p);
  const float* rg; int HW;
  if (lvl == 0) { rg = r0; HW = A0; }
  else if (lvl == 1) { rg = r1; HW = A1; }
  else { rg = r2; HW = A2; }
  const float* base = rg + ((size_t)b * NREG) * HW + p;
  float dist[4], ml[4];
  for (int sd = 0; sd < 4; ++sd) {
    float x[16]; float mx = -1e30f;
    for (int r = 0; r < 16; ++r) { x[r] = base[(size_t)(sd * 16 + r) * HW]; mx = fmaxf(mx, x[r]); }
    float se = 0.f, wsum = 0.f;
    for (int r = 0; r < 16; ++r) { float e = __expf(x[r] - mx); se += e; wsum += e * (float)r; }
    dist[sd] = wsum / se;
    ml[sd] = mx + __logf(se);
  }
  bb[t]  = make_float4(ax - dist[0], ay - dist[1], ax + dist[2], ay + dist[3]);
  mls[t] = make_float4(ml[0], ml[1], ml[2], ml[3]);
}

// 2: build compacted candidate lists per (b,m): masked anchors with align metric
__global__ __launch_bounds__(256) void k_cand(const float* boxes, const int* labels,
                                              const float4* bb,
                                              const float* c0, const float* c1, const float* c2,
                                              int* cand_cnt, float* cand_val, int* cand_idx) {
  int blk = blockIdx.x;           // bm * 33 + chunk
  int bm = blk / 33, chunk = blk % 33;
  int a = chunk * 256 + threadIdx.x;
  int b = bm / NM, m = bm % NM;
  float gx1, gy1, gx2, gy2; bool valid;
  gtbox(boxes, b, m, gx1, gy1, gx2, gy2, valid);
  bool pred = false; float am = 0.f;
  if (a < NA && valid) {
    float ax, ay, s; int lvl, p;
    anch(a, ax, ay, s, lvl, p);
    float axp = ax * s, ayp = ay * s;
    float mn = fminf(fminf(axp - gx1, ayp - gy1), fminf(gx2 - axp, gy2 - ayp));
    if (mn > 1e-9f) {
      pred = true;
      float4 pb = bb[(size_t)b * NA + a];
      float c = ciou_f(gx1, gy1, gx2, gy2, pb.x * s, pb.y * s, pb.z * s, pb.w * s);
      float o = fmaxf(c, 0.f);
      int lbl = labels[bm]; if (lbl < 0) lbl = 0; if (lbl >= NCC) lbl = NCC - 1;
      float x = cls_at(c0, c1, c2, b, lbl, a);
      float sc = 1.f / (1.f + expf(-x));
      am = align_of(sc, o);
    }
  }
  unsigned long long mask = __ballot(pred);
  if (mask) {
    int lane = threadIdx.x & 63;
    int nact = __popcll(mask);
    int leader = __ffsll(mask) - 1;
    int base = 0;
    if (lane == leader) base = atomicAdd(&cand_cnt[bm], nact);
    base = __shfl(base, leader);
    if (pred) {
      int off = base + __popcll(mask & ((1ull << lane) - 1ull));
      if (off < CAP) { cand_val[(size_t)bm * CAP + off] = am; cand_idx[(size_t)bm * CAP + off] = a; }
    }
  }
}

// 3: top-10 per (b,m) over compacted candidates; exact lax.top_k tie semantics
__global__ __launch_bounds__(64) void k_topk2(const int* cand_cnt, const float* cand_val,
                                              const int* cand_idx, int* fgcnt, int* msum) {
  __shared__ float sv[CAP];
  __shared__ int   si[CAP];
  int bm = blockIdx.x;
  int b = bm / NM, m = bm % NM;
  int lane = threadIdx.x;
  int n = cand_cnt[bm]; if (n > CAP) n = CAP;
  if (n == 0) return;
  for (int j = lane; j < n; j += 64) {
    sv[j] = cand_val[(size_t)bm * CAP + j];
    si[j] = cand_idx[(size_t)bm * CAP + j];
  }
  __syncthreads();
  // count positives
  int cnt = 0;
  for (int j = lane; j < n; j += 64) if (sv[j] > 0.f) cnt++;
  for (int o = 32; o; o >>= 1) cnt += __shfl_xor(cnt, o);
  int npos = cnt;

  if (npos > 10) {
    for (int k = 0; k < 10; ++k) {
      float bv = -1.f; int bi = 1 << 30;
      for (int j = lane; j < n; j += 64) {
        float v = sv[j]; int ix = si[j];
        if (v > bv || (v == bv && ix < bi)) { bv = v; bi = ix; }
      }
      for (int o = 32; o; o >>= 1) {
        float v = __shfl_xor(bv, o); int ix = __shfl_xor(bi, o);
        if (v > bv || (v == bv && ix < bi)) { bv = v; bi = ix; }
      }
      for (int j = lane; j < n; j += 64) if (si[j] == bi) sv[j] = -1.f;
      if (lane == 0) {
        atomicAdd(&fgcnt[(size_t)b * NA + bi], 1);
        atomicAdd(&msum[(size_t)b * NA + bi], m);
      }
      __syncthreads();
    }
  } else {
    // all positive candidates are picked
    for (int j = lane; j < n; j += 64) {
      if (sv[j] > 0.f) {
        atomicAdd(&fgcnt[(size_t)b * NA + si[j]], 1);
        atomicAdd(&msum[(size_t)b * NA + si[j]], m);
      }
    }
    // zero-tie fill: zero-am candidate at anchor i picked iff i - pos_below(i) < 10-npos
    // (requires i < 10 — rare corner)
    int need = 10 - npos;
    for (int j = lane; j < n; j += 64) {
      if (sv[j] == 0.f) {
        int i = si[j];
        if (i < 10) {
          int pb = 0;
          for (int q = 0; q < n; ++q) pb += (sv[q] > 0.f && si[q] < i) ? 1 : 0;
          if (i - pb < need) {
            atomicAdd(&fgcnt[(size_t)b * NA + i], 1);
            atomicAdd(&msum[(size_t)b * NA + i], m);
          }
        }
      }
    }
  }
}

// 4: resolve assignment (fg>1 -> overlap argmax, recomputed) + per-gt maxima
__global__ __launch_bounds__(256) void k_resolve(const float* boxes, const int* labels,
                                                 const float4* bb,
                                                 const float* c0, const float* c1, const float* c2,
                                                 const int* fgcnt, const int* msum,
                                                 int* assign, float* amv,
                                                 unsigned* pos_am, unsigned* pos_ov) {
  int t = blockIdx.x * blockDim.x + threadIdx.x;
  if (t >= NB * NA) return;
  int b = t / NA, a = t % NA;
  int fg = fgcnt[t];
  int asn = -1; float o = 0.f;
  if (fg > 0) {
    float ax, ay, s; int lvl, p;
    anch(a, ax, ay, s, lvl, p);
    float axp = ax * s, ayp = ay * s;
    float4 pb = bb[t];
    float px1 = pb.x * s, py1 = pb.y * s, px2 = pb.z * s, py2 = pb.w * s;
    if (fg == 1) {
      asn = msum[t];
      float gx1, gy1, gx2, gy2; bool valid;
      gtbox(boxes, b, asn, gx1, gy1, gx2, gy2, valid);
      o = fmaxf(ciou_f(gx1, gy1, gx2, gy2, px1, py1, px2, py2), 0.f);
    } else {
      float bv = -1e30f; int bi = 0;
      for (int m = 0; m < NM; ++m) {
        float gx1, gy1, gx2, gy2; bool valid;
        gtbox(boxes, b, m, gx1, gy1, gx2, gy2, valid);
        float om = 0.f;
        if (valid) {
          float mn = fminf(fminf(axp - gx1, ayp - gy1), fminf(gx2 - axp, gy2 - ayp));
          if (mn > 1e-9f)
            om = fmaxf(ciou_f(gx1, gy1, gx2, gy2, px1, py1, px2, py2), 0.f);
        }
        if (om > bv) { bv = om; bi = m; }
      }
      asn = bi; o = bv;
    }
    float am = 0.f;
    if (o > 0.f) {
      int lbl = labels[b * NM + asn]; if (lbl < 0) lbl = 0; if (lbl >= NCC) lbl = NCC - 1;
      float x = cls_at(c0, c1, c2, b, lbl, a);
      float sc = 1.f / (1.f + expf(-x));
      am = align_of(sc, o);
      atomicMax(&pos_am[b * NM + asn], __float_as_uint(am));
      atomicMax(&pos_ov[b * NM + asn], __float_as_uint(o));
    }
    amv[t] = am;
  }
  assign[t] = asn;
}

// 5: per-assigned-anchor loss terms -> block-reduced, one atomic per term per block
__global__ __launch_bounds__(256) void k_posloss(const float* c0, const float* c1, const float* c2,
    const float* r0, const float* r1, const float* r2,
    const float* boxes, const int* labels, const int* assign, const float* amv,
    const float4* bb, const float4* mls, const unsigned* pos_am, const unsigned* pos_ov,
    double* acc) {
  int t = blockIdx.x * blockDim.x + threadIdx.x;
  double t_norm = 0.0, t_x = 0.0, t_iou = 0.0, t_dfl = 0.0;
  int asn = (t < NB * NA) ? assign[t] : -1;
  if (asn >= 0) {
    int b = t / NA, a = t % NA;
    float pam = __uint_as_float(pos_am[b * NM + asn]);
    float pov = __uint_as_float(pos_ov[b * NM + asn]);
    float norm = amv[t] * pov / (pam + 1e-9f);
    int lbl = labels[b * NM + asn]; if (lbl < 0) lbl = 0; if (lbl >= NCC) lbl = NCC - 1;
    float x = cls_at(c0, c1, c2, b, lbl, a);
    float gx1, gy1, gx2, gy2; bool valid;
    gtbox(boxes, b, asn, gx1, gy1, gx2, gy2, valid);
    float ax, ay, s; int lvl, p;
    anch(a, ax, ay, s, lvl, p);
    float inv_s = 1.f / s;
    float tx1 = gx1 * inv_s, ty1 = gy1 * inv_s, tx2 = gx2 * inv_s, ty2 = gy2 * inv_s;
    float4 pb = bb[t];
    float iou = ciou_f(pb.x, pb.y, pb.z, pb.w, tx1, ty1, tx2, ty2);
    float4 ml = mls[t];
    float tgt[4] = { ax - tx1, ay - ty1, tx2 - ax, ty2 - ay };
    float mlv[4] = { ml.x, ml.y, ml.z, ml.w };
    float dfl = 0.f;
    for (int sd = 0; sd < 4; ++sd) {
      float tv = fminf(fmaxf(tgt[sd], 0.f), 14.99f);
      float tlf = floorf(tv);
      int tl = (int)tlf;
      float wl = (tlf + 1.f) - tv;
      float xtl = reg_at(r0, r1, r2, b, sd * 16 + tl,     lvl, p);
      float xtr = reg_at(r0, r1, r2, b, sd * 16 + tl + 1, lvl, p);
      dfl += -((xtl - mlv[sd]) * wl + (xtr - mlv[sd]) * (1.f - wl));
    }
    dfl *= 0.25f;
    t_norm = (double)norm;
    t_x    = (double)(norm * x);
    t_iou  = (double)((1.f - iou) * norm);
    t_dfl  = (double)(dfl * norm);
  }
  __shared__ double sred[256];
  double vals[4] = { t_norm, t_x, t_iou, t_dfl };
  const int slots[4] = { 2, 1, 3, 4 };
  for (int q = 0; q < 4; ++q) {
    sred[threadIdx.x] = vals[q];
    __syncthreads();
    for (int off = 128; off; off >>= 1) {
      if (threadIdx.x < off) sred[threadIdx.x] += sred[threadIdx.x + off];
      __syncthreads();
    }
    if (threadIdx.x == 0 && sred[0] != 0.0)
      atomicAdd(&acc[slots[q] * ACC_STRIDE], sred[0]);
    __syncthreads();
  }
}

// 6: sum of softplus over all class logits (float4 vectorized, fast transcendentals)
__global__ __launch_bounds__(256) void k_bce(const float4* c0, const float4* c1, const float4* c2,
                                             double* acc) {
  const size_t N0 = (size_t)NB * NCC * A0 / 4;
  const size_t N1 = (size_t)NB * NCC * A1 / 4;
  const size_t N2 = (size_t)NB * NCC * A2 / 4;
  const size_t NT = N0 + N1 + N2;
  size_t i0 = (size_t)blockIdx.x * blockDim.x + threadIdx.x;
  size_t stride = (size_t)gridDim.x * blockDim.x;
  float s0 = 0.f, s1 = 0.f;
  for (size_t i = i0; i < NT; i += stride) {
    float4 v;
    if (i < N0) v = c0[i];
    else if (i < N0 + N1) v = c1[i - N0];
    else v = c2[i - N0 - N1];
    s0 += softplus_fast(v.x) + softplus_fast(v.z);
    s1 += softplus_fast(v.y) + softplus_fast(v.w);
  }
  float lsum = s0 + s1;
  __shared__ float sred[256];
  sred[threadIdx.x] = lsum;
  __syncthreads();
  for (int off = 128; off; off >>= 1) {
    if (threadIdx.x < off) sred[threadIdx.x] += sred[threadIdx.x + off];
    __syncthreads();
  }
  if (threadIdx.x == 0) atomicAdd(&acc[0], (double)sred[0]);
}

// 7: compose outputs
__global__ void k_final(const double* acc, float* out) {
  if (blockIdx.x == 0 && threadIdx.x == 0) {
    double tss = acc[2 * ACC_STRIDE]; if (tss < 1.0) tss = 1.0;
    double l0 = 0.5 * (acc[0] - acc[1 * ACC_STRIDE]) / tss;
    double l1 = 7.5 * acc[3 * ACC_STRIDE] / tss;
    double l2 = 1.5 * acc[4 * ACC_STRIDE] / tss;
    out[0] = (float)(l0 + l1 + l2);
    out[1] = (float)l0;
    out[2] = (float)l1;
    out[3] = (float)l2;
  }
}

// ---------- launch ----------

extern "C" void kernel_launch(void* const* d_in, const int* in_sizes, int n_in,
                              void* d_out, int out_size, void* d_ws, size_t ws_size,
                              hipStream_t stream) {
  (void)in_sizes; (void)n_in; (void)out_size; (void)ws_size;
  const float* cls0  = (const float*)d_in[0];
  const float* cls1  = (const float*)d_in[1];
  const float* cls2  = (const float*)d_in[2];
  const float* reg0  = (const float*)d_in[3];
  const float* reg1  = (const float*)d_in[4];
  const float* reg2  = (const float*)d_in[5];
  const float* boxes = (const float*)d_in[6];
  const int*   labels = (const int*)d_in[7];
  float* out = (float*)d_out;

  const size_t BA = (size_t)NB * NA;  // 134400
  const int    BM = NB * NM;          // 512

  char* wsb = (char*)d_ws;
  double*   acc      = (double*)wsb;                       // ACC_SLOTS*ACC_STRIDE doubles
  unsigned* pos_am   = (unsigned*)(acc + ACC_SLOTS * ACC_STRIDE); // BM
  unsigned* pos_ov   = pos_am + BM;                        // BM
  int*      cand_cnt = (int*)(pos_ov + BM);                // BM
  int*      fgcnt    = cand_cnt + BM;                      // BA
  int*      msum     = fgcnt + BA;                         // BA
  float*    bb       = (float*)(msum + BA);                // BA*4
  float*    mls      = bb + BA * 4;                        // BA*4
  float*    amv      = mls + BA * 4;                       // BA
  int*      assign   = (int*)(amv + BA);                   // BA
  float*    cand_val = (float*)(assign + BA);              // BM*CAP
  int*      cand_idx = (int*)(cand_val + (size_t)BM * CAP);// BM*CAP

  k_decode<<<525, 256, 0, stream>>>(reg0, reg1, reg2, (float4*)bb, (float4*)mls,
                                    fgcnt, msum, cand_cnt, pos_am, pos_ov, acc);
  k_cand<<<BM * 33, 256, 0, stream>>>(boxes, labels, (const float4*)bb,
                                      cls0, cls1, cls2, cand_cnt, cand_val, cand_idx);
  k_topk2<<<BM, 64, 0, stream>>>(cand_cnt, cand_val, cand_idx, fgcnt, msum);
  k_resolve<<<525, 256, 0, stream>>>(boxes, labels, (const float4*)bb, cls0, cls1, cls2,
                                     fgcnt, msum, assign, amv, pos_am, pos_ov);
  k_posloss<<<525, 256, 0, stream>>>(cls0, cls1, cls2, reg0, reg1, reg2,
                                     boxes, labels, assign, amv,
                                     (const float4*)bb, (const float4*)mls, pos_am, pos_ov, acc);
  k_bce<<<2048, 256, 0, stream>>>((const float4*)cls0, (const float4*)cls1, (const float4*)cls2, acc);
  k_final<<<1, 64, 0, stream>>>(acc, out);
}